// Round 6
// baseline (217174.756 us; speedup 1.0000x reference)
//
#include <hip/hip_runtime.h>
#include <math.h>

#define B_    16
#define L_    2048
#define LM1   2047
#define D_    1024
#define H_    512
#define TBLK  64
#define NBLK  32   // ceil(2047/64)
#define NWG   256

// ---------------------------------------------------------------------------
// lean grid barrier: device-global {cnt, gen}; only thread 0 per WG spins.
// gen is monotonic across calls/replays (logic is generation-relative).
// ---------------------------------------------------------------------------
__device__ int g_bar[2] = {0, 0};

__device__ __forceinline__ void gbar()
{
    __syncthreads();
    if (threadIdx.x == 0) {
        __threadfence();   // make this WG's stores device-visible (L2 wb)
        int* cnt = &g_bar[0];
        int* gen = &g_bar[1];
        const int g = __hip_atomic_load(gen, __ATOMIC_ACQUIRE, __HIP_MEMORY_SCOPE_AGENT);
        if (__hip_atomic_fetch_add(cnt, 1, __ATOMIC_ACQ_REL, __HIP_MEMORY_SCOPE_AGENT) == NWG - 1) {
            __hip_atomic_store(cnt, 0, __ATOMIC_RELAXED, __HIP_MEMORY_SCOPE_AGENT);
            __hip_atomic_store(gen, g + 1, __ATOMIC_RELEASE, __HIP_MEMORY_SCOPE_AGENT);
        } else {
            while (__hip_atomic_load(gen, __ATOMIC_ACQUIRE, __HIP_MEMORY_SCOPE_AGENT) == g)
                __builtin_amdgcn_s_sleep(2);
        }
        __threadfence();   // invalidate stale caches before consuming others' data
    }
    __syncthreads();
}

// ---------------------------------------------------------------------------
// K[r][n] = sum_d x[b*L+t][d] * Wcat[n][d],  r = b*LM1 + t, n in [0,1024)
// grid (512, 16), block 256
// ---------------------------------------------------------------------------
__global__ void k_proj(const float* __restrict__ x, const float* __restrict__ Wsem,
                       const float* __restrict__ Wepi, float* __restrict__ K)
{
    __shared__ float As[16][68];
    __shared__ float Bs[16][68];
    const int tid = threadIdx.x;
    const int tx = tid & 15, ty = tid >> 4;
    const int r0 = blockIdx.x * 64;
    const int n0 = blockIdx.y * 64;
    const int lr  = tid >> 2;
    const int lk4 = (tid & 3) << 2;
    const int rowg = r0 + lr;
    const bool rok = rowg < B_ * LM1;
    const int rowc = rok ? rowg : 0;
    const int bb = rowc / LM1;
    const int tt = rowc - bb * LM1;
    const float* xrow = x + ((size_t)bb * L_ + tt) * D_;
    const int nW = n0 + lr;
    const float* wrow = (nW < H_) ? (Wsem + (size_t)nW * D_)
                                  : (Wepi + (size_t)(nW - H_) * D_);
    float acc[4][4];
#pragma unroll
    for (int i = 0; i < 4; ++i)
#pragma unroll
        for (int j = 0; j < 4; ++j) acc[i][j] = 0.f;

    for (int kk = 0; kk < D_; kk += 16) {
        const float4 av = rok ? *(const float4*)(xrow + kk + lk4) : make_float4(0.f,0.f,0.f,0.f);
        const float4 bv = *(const float4*)(wrow + kk + lk4);
        As[lk4+0][lr] = av.x; As[lk4+1][lr] = av.y; As[lk4+2][lr] = av.z; As[lk4+3][lr] = av.w;
        Bs[lk4+0][lr] = bv.x; Bs[lk4+1][lr] = bv.y; Bs[lk4+2][lr] = bv.z; Bs[lk4+3][lr] = bv.w;
        __syncthreads();
#pragma unroll
        for (int k = 0; k < 16; ++k) {
            const float4 a4 = *(const float4*)&As[k][ty << 2];
            const float4 b4 = *(const float4*)&Bs[k][tx << 2];
            const float aa[4] = {a4.x, a4.y, a4.z, a4.w};
            const float bbv[4] = {b4.x, b4.y, b4.z, b4.w};
#pragma unroll
            for (int i = 0; i < 4; ++i)
#pragma unroll
                for (int j = 0; j < 4; ++j)
                    acc[i][j] = fmaf(aa[i], bbv[j], acc[i][j]);
        }
        __syncthreads();
    }
#pragma unroll
    for (int i = 0; i < 4; ++i) {
        const int r = r0 + (ty << 2) + i;
        if (r < B_ * LM1)
            *(float4*)(K + (size_t)r * D_ + n0 + (tx << 2)) =
                make_float4(acc[i][0], acc[i][1], acc[i][2], acc[i][3]);
    }
}

// ---------------------------------------------------------------------------
// squared norms + reciprocal norms per (b, m, t).  grid B_*LM1, block 256
// ---------------------------------------------------------------------------
__global__ void k_norms(const float* __restrict__ K, float* __restrict__ nk2,
                        float* __restrict__ rn)
{
    const int r = blockIdx.x;               // b*LM1 + t
    const int tid = threadIdx.x;            // 256
    const float4 v = *(const float4*)(K + (size_t)r * D_ + (tid << 2));
    float s = v.x*v.x + v.y*v.y + v.z*v.z + v.w*v.w;
#pragma unroll
    for (int o = 32; o; o >>= 1) s += __shfl_xor(s, o);
    __shared__ float part[4];
    const int wid = tid >> 6, lane = tid & 63;
    if (lane == 0) part[wid] = s;
    __syncthreads();
    if (tid == 0) {
        const int b = r / LM1, t = r - b * LM1;
        const float s0 = part[0] + part[1];
        const float s1 = part[2] + part[3];
        nk2[(size_t)(b*2+0)*LM1 + t] = s0;
        nk2[(size_t)(b*2+1)*LM1 + t] = s1;
        rn [(size_t)(b*2+0)*LM1 + t] = 1.f / fmaxf(sqrtf(s0), 1e-12f);
        rn [(size_t)(b*2+1)*LM1 + t] = 1.f / fmaxf(sqrtf(s1), 1e-12f);
    }
}

// ---------------------------------------------------------------------------
// Gram (all blocks, hoisted): G[bm][blk][t][d] = kn_t . kn_{t+d}   (shifted)
// grid (NBLK, B_*2), block 256.  Tail entries (t+d>63) zeroed explicitly so
// the scan never reads poisoned workspace.
// ---------------------------------------------------------------------------
__global__ void k_gram(const float* __restrict__ K, const float* __restrict__ rn,
                       float* __restrict__ G)
{
    const int blk = blockIdx.x;
    const int bm  = blockIdx.y;
    const int b = bm >> 1, m = bm & 1;
    const int t0 = blk * TBLK;
    const int Tb = (LM1 - t0 < TBLK) ? (LM1 - t0) : TBLK;
    __shared__ float As[16][68];
    const int tid = threadIdx.x;
    const int tx = tid & 15, ty = tid >> 4;
    const int lr = tid >> 2, lk4 = (tid & 3) << 2;
    const float* Abase = K + ((size_t)(b * LM1 + t0)) * D_ + m * H_;
    float acc[4][4];
#pragma unroll
    for (int i = 0; i < 4; ++i)
#pragma unroll
        for (int j = 0; j < 4; ++j) acc[i][j] = 0.f;

    for (int kk = 0; kk < H_; kk += 16) {
        const float4 av = (lr < Tb) ? *(const float4*)(Abase + (size_t)lr * D_ + kk + lk4)
                                    : make_float4(0.f,0.f,0.f,0.f);
        As[lk4+0][lr] = av.x; As[lk4+1][lr] = av.y; As[lk4+2][lr] = av.z; As[lk4+3][lr] = av.w;
        __syncthreads();
#pragma unroll
        for (int k = 0; k < 16; ++k) {
            const float4 a4 = *(const float4*)&As[k][ty << 2];
            const float4 b4 = *(const float4*)&As[k][tx << 2];
            const float aa[4] = {a4.x, a4.y, a4.z, a4.w};
            const float bbv[4] = {b4.x, b4.y, b4.z, b4.w};
#pragma unroll
            for (int i = 0; i < 4; ++i)
#pragma unroll
                for (int j = 0; j < 4; ++j)
                    acc[i][j] = fmaf(aa[i], bbv[j], acc[i][j]);
        }
        __syncthreads();
    }
    const float* rnb = rn + (size_t)bm * LM1 + t0;
    float* Gout = G + ((size_t)bm * NBLK + blk) * (TBLK * TBLK);
#pragma unroll
    for (int i = 0; i < 4; ++i) {
        const int t = (ty << 2) + i;
        const float rt = (t < Tb) ? rnb[t] : 0.f;
#pragma unroll
        for (int j = 0; j < 4; ++j) {
            const int s = (tx << 2) + j;
            const int d = s - t;
            if (d >= 0) {
                const float val = (t < Tb && s < Tb) ? rt * rnb[s] * acc[i][j] : 0.f;
                Gout[(size_t)t * TBLK + d] = val;
            }
        }
    }
    // zero never-written tail (t + d > 63)
    for (int idx = tid; idx < TBLK * TBLK; idx += 256) {
        const int t = idx >> 6, d = idx & 63;
        if (t + d > 63) Gout[idx] = 0.f;
    }
}

// one chunk of the pending-shift chain
#define CH4(g,pA,pB,pC,pD,pE) \
    pA = fmaf(g.x, vv, pB); pB = fmaf(g.y, vv, pC); \
    pC = fmaf(g.z, vv, pD); pD = fmaf(g.w, vv, pE);

// ---------------------------------------------------------------------------
// Fused scan, 256 WGs x 1024 threads, 1 WG/CU (launch_bounds (1024,4): 4
// waves/EU min -> 128 VGPR cap).  M is REGISTER-RESIDENT:
//   wg 0..15   : Phase-B (sequential scan) specialists, no M slabs
//   wg 16..31  : own 2 slabs (64 rows x 512) of M[bm], bm = 0..3
//   wg 32..255 : own 1 slab, bm = wg>>3
// Thread layout per slab: rl = tid>>4 (row), jc = tid&15, j = jc + 16*jj
// (stride-16 j ownership -> conflict-free LDS broadcast reads).
// Per blk: [A: Vext from Mreg] bar [B: seq scan] bar [C: Mreg update] (no bar)
// ---------------------------------------------------------------------------
__global__ void __launch_bounds__(1024, 4) k_scan(
    const float* __restrict__ K, const float* __restrict__ rn,
    const float* __restrict__ nk2, const float* __restrict__ G,
    float* __restrict__ Mm, float* __restrict__ Vext, float* __restrict__ AU,
    float omA)
{
    const int wg  = blockIdx.x;
    const int tid = threadIdx.x;
    __shared__ float sh[10240];     // A/C: Kt 8192 + AUt 1024 + AUt2 1024 | B: G 8192
    __shared__ float part[32];

    const int rl = tid >> 4;        // 0..63
    const int jc = tid & 15;        // 0..15

    // slab ownership
    const bool owner = (wg >= 16);
    const int  s0 = (wg >= 32) ? wg : ((wg - 16) << 1);
    const int  ns = (wg >= 32) ? 1 : 2;
    const int  bmO = s0 >> 3;
    const int  bO  = bmO >> 1, mO = bmO & 1;
    const int  i0a = (s0 & 7) << 6;
    const int  i0b = ((s0 + 1) & 7) << 6;

    float MregA[32], MregB[32];
#pragma unroll
    for (int jj = 0; jj < 32; ++jj) { MregA[jj] = 0.f; MregB[jj] = 0.f; }

    for (int blk = 0; blk < NBLK; ++blk) {
        const int t0 = blk * TBLK;
        const int Tb = (LM1 - t0 < TBLK) ? (LM1 - t0) : TBLK;

        // ---------------- Phase A : Vext = rn ⊙ (K_blk @ Mreg^T) ----------------
        if (owner) {
            for (int tc = 0; tc < 4; ++tc) {
                // stage rn-scaled K tile [16][512]
#pragma unroll
                for (int vv2 = 0; vv2 < 2; ++vv2) {
                    const int v = tid + (vv2 << 10);
                    const int q = v >> 7, c4 = v & 127;
                    const int t = (tc << 4) + q;
                    float4 val = make_float4(0.f, 0.f, 0.f, 0.f);
                    if (t < Tb) {
                        val = *(const float4*)(K + ((size_t)(bO * LM1 + t0 + t)) * D_ + mO * H_ + (c4 << 2));
                        const float rv = rn[(size_t)bmO * LM1 + t0 + t];
                        val.x *= rv; val.y *= rv; val.z *= rv; val.w *= rv;
                    }
                    *(float4*)(sh + (q << 9) + (c4 << 2)) = val;
                }
                __syncthreads();
                for (int q = 0; q < 16; ++q) {
                    const float* kr = sh + (q << 9);
                    float sA = 0.f, sB = 0.f;
#pragma unroll
                    for (int jj = 0; jj < 32; ++jj) {
                        const float kv = kr[jc + (jj << 4)];
                        sA = fmaf(MregA[jj], kv, sA);
                        if (ns == 2) sB = fmaf(MregB[jj], kv, sB);
                    }
                    sA += __shfl_xor(sA, 1); sA += __shfl_xor(sA, 2);
                    sA += __shfl_xor(sA, 4); sA += __shfl_xor(sA, 8);
                    if (ns == 2) {
                        sB += __shfl_xor(sB, 1); sB += __shfl_xor(sB, 2);
                        sB += __shfl_xor(sB, 4); sB += __shfl_xor(sB, 8);
                    }
                    const int t = (tc << 4) + q;
                    if (jc == 0 && t < Tb) {
                        Vext[((size_t)bmO * TBLK + t) * H_ + i0a + rl] = sA;
                        if (ns == 2) Vext[((size_t)bmO * TBLK + t) * H_ + i0b + rl] = sB;
                    }
                }
                __syncthreads();
            }
        }
        gbar();   // Vext ready

        // ---------------- Phase B (seq): wg < 16, thread = (m, j) ----------------
        if (wg < B_) {
            const int b = wg;
            const int m = tid >> 9;
            const int wid = tid >> 6, lane = tid & 63;
            {
                const float4* g0 = (const float4*)(G + ((size_t)(b*2+0) * NBLK + blk) * (TBLK*TBLK));
                const float4* g1 = (const float4*)(G + ((size_t)(b*2+1) * NBLK + blk) * (TBLK*TBLK));
                float4* dst = (float4*)sh;
                dst[tid]        = g0[tid];
                dst[tid + 1024] = g1[tid];
            }
            float p00=0.f,p01=0.f,p02=0.f,p03=0.f,p04=0.f,p05=0.f,p06=0.f,p07=0.f;
            float p08=0.f,p09=0.f,p10=0.f,p11=0.f,p12=0.f,p13=0.f,p14=0.f,p15=0.f;
            float p16=0.f,p17=0.f,p18=0.f,p19=0.f,p20=0.f,p21=0.f,p22=0.f,p23=0.f;
            float p24=0.f,p25=0.f,p26=0.f,p27=0.f,p28=0.f,p29=0.f,p30=0.f,p31=0.f;
            float p32=0.f,p33=0.f,p34=0.f,p35=0.f,p36=0.f,p37=0.f,p38=0.f,p39=0.f;
            float p40=0.f,p41=0.f,p42=0.f,p43=0.f,p44=0.f,p45=0.f,p46=0.f,p47=0.f;
            float p48=0.f,p49=0.f,p50=0.f,p51=0.f,p52=0.f,p53=0.f,p54=0.f,p55=0.f;
            float p56=0.f,p57=0.f,p58=0.f,p59=0.f,p60=0.f,p61=0.f,p62=0.f,p63=0.f;
            __syncthreads();

            const float* Kb  = K + ((size_t)(b * LM1 + t0)) * D_ + tid;   // m*H_+j == tid
            const float* Vb  = Vext + ((size_t)(b*2+m) * TBLK) * H_ + (tid & 511);
            float* AUp       = AU   + ((size_t)(b*2+m) * TBLK) * H_ + (tid & 511);
            const float* qs  = nk2 + (size_t)(b*2+0) * LM1 + t0;
            const float* qe  = nk2 + (size_t)(b*2+1) * LM1 + t0;
            const float* Gm  = sh + (m << 12);

            float kc = Kb[0], vc = Vb[0];
            float ncs = qs[0], nce = qe[0];

            for (int t = 0; t < Tb; ++t) {
                const float u = kc - vc - p00;
                float kn = 0.f, vn = 0.f, nns = 0.f, nne = 0.f;
                if (t + 1 < Tb) {
                    kn  = Kb[(size_t)(t+1) * D_];
                    vn  = Vb[(t+1) * H_];
                    nns = qs[t+1];
                    nne = qe[t+1];
                }
                float s = u * u;
                s += __shfl_xor(s, 32); s += __shfl_xor(s, 16); s += __shfl_xor(s, 8);
                s += __shfl_xor(s, 4);  s += __shfl_xor(s, 2);  s += __shfl_xor(s, 1);
                float* pp = &part[(t & 1) << 4];
                if (lane == 0) pp[wid] = s;
                // raw barrier: drain LDS only; global loads/stores stay in flight
                asm volatile("s_waitcnt lgkmcnt(0)" ::: "memory");
                __builtin_amdgcn_s_barrier();
                __builtin_amdgcn_sched_barrier(0);
                float Ns = 0.f, Ne = 0.f;
#pragma unroll
                for (int i = 0; i < 8; ++i) { Ns += pp[i]; Ne += pp[i + 8]; }
                const bool fire = (Ns >= 0.49f * ncs) || (Ne >= 0.49f * nce);
                const float w = (float)(t0 + t + 1) * (1.0f / (float)L_);
                const float scale = m ? (omA * w) : omA;
                const float vv = fire ? scale * u : 0.f;   // vv==0 -> exact shift
                AUp[(size_t)t * H_] = vv;

                const float4* Gr = (const float4*)(Gm + (t << 6));
                float4 gA = Gr[0], gB = Gr[1];
                p00 = fmaf(gA.y, vv, p01); p01 = fmaf(gA.z, vv, p02); p02 = fmaf(gA.w, vv, p03);
                gA = Gr[2];
                CH4(gB, p03,p04,p05,p06,p07)  gB = Gr[3];
                CH4(gA, p07,p08,p09,p10,p11)  gA = Gr[4];
                CH4(gB, p11,p12,p13,p14,p15)  gB = Gr[5];
                CH4(gA, p15,p16,p17,p18,p19)  gA = Gr[6];
                CH4(gB, p19,p20,p21,p22,p23)  gB = Gr[7];
                CH4(gA, p23,p24,p25,p26,p27)  gA = Gr[8];
                CH4(gB, p27,p28,p29,p30,p31)  gB = Gr[9];
                CH4(gA, p31,p32,p33,p34,p35)  gA = Gr[10];
                CH4(gB, p35,p36,p37,p38,p39)  gB = Gr[11];
                CH4(gA, p39,p40,p41,p42,p43)  gA = Gr[12];
                CH4(gB, p43,p44,p45,p46,p47)  gB = Gr[13];
                CH4(gA, p47,p48,p49,p50,p51)  gA = Gr[14];
                CH4(gB, p51,p52,p53,p54,p55)  gB = Gr[15];
                CH4(gA, p55,p56,p57,p58,p59)
                CH4(gB, p59,p60,p61,p62,p63)
                p63 = 0.f;

                kc = kn; vc = vn; ncs = nns; nce = nne;
            }
        }
        gbar();   // AU ready

        // ---------------- Phase C : Mreg += (a∘U)^T (rn ⊙ K_blk) ----------------
        if (owner) {
            for (int tc = 0; tc < 4; ++tc) {
                // stage rn-scaled K tile
#pragma unroll
                for (int vv2 = 0; vv2 < 2; ++vv2) {
                    const int v = tid + (vv2 << 10);
                    const int q = v >> 7, c4 = v & 127;
                    const int t = (tc << 4) + q;
                    float4 val = make_float4(0.f, 0.f, 0.f, 0.f);
                    if (t < Tb) {
                        val = *(const float4*)(K + ((size_t)(bO * LM1 + t0 + t)) * D_ + mO * H_ + (c4 << 2));
                        const float rv = rn[(size_t)bmO * LM1 + t0 + t];
                        val.x *= rv; val.y *= rv; val.z *= rv; val.w *= rv;
                    }
                    *(float4*)(sh + (q << 9) + (c4 << 2)) = val;
                }
                // stage AU tiles [16][64]
                if (tid < 256) {
                    const int q = tid >> 4, r4 = (tid & 15) << 2;
                    const int t = (tc << 4) + q;
                    float4 a = make_float4(0.f, 0.f, 0.f, 0.f);
                    if (t < Tb) a = *(const float4*)(AU + ((size_t)bmO * TBLK + t) * H_ + i0a + r4);
                    *(float4*)(sh + 8192 + (q << 6) + r4) = a;
                } else if (tid < 512 && ns == 2) {
                    const int v2 = tid - 256;
                    const int q = v2 >> 4, r4 = (v2 & 15) << 2;
                    const int t = (tc << 4) + q;
                    float4 a = make_float4(0.f, 0.f, 0.f, 0.f);
                    if (t < Tb) a = *(const float4*)(AU + ((size_t)bmO * TBLK + t) * H_ + i0b + r4);
                    *(float4*)(sh + 9216 + (q << 6) + r4) = a;
                }
                __syncthreads();
                for (int q = 0; q < 16; ++q) {
                    const float* kr = sh + (q << 9);
                    const float aA = sh[8192 + (q << 6) + rl];
                    const float aB = (ns == 2) ? sh[9216 + (q << 6) + rl] : 0.f;
#pragma unroll
                    for (int jj = 0; jj < 32; ++jj) {
                        const float kv = kr[jc + (jj << 4)];
                        MregA[jj] = fmaf(aA, kv, MregA[jj]);
                        if (ns == 2) MregB[jj] = fmaf(aB, kv, MregB[jj]);
                    }
                }
                __syncthreads();
            }
        }
        // no barrier needed: next Phase A reads only this WG's own Mreg
    }

    // flush register M to global for the query path
    if (owner) {
        float* MrA = Mm + ((size_t)bmO * H_ + i0a + rl) * H_ + jc;
#pragma unroll
        for (int jj = 0; jj < 32; ++jj) MrA[jj << 4] = MregA[jj];
        if (ns == 2) {
            float* MrB = Mm + ((size_t)bmO * H_ + i0b + rl) * H_ + jc;
#pragma unroll
            for (int jj = 0; jj < 32; ++jj) MrB[jj << 4] = MregB[jj];
        }
    }
}

// ---------------------------------------------------------------------------
// query path: qn (normalized projections) + gnull.  grid B_, block 1024
// ---------------------------------------------------------------------------
__global__ void __launch_bounds__(1024) k_q(
    const float* __restrict__ x, const float* __restrict__ Wsem,
    const float* __restrict__ Wepi, const float* __restrict__ nw,
    const float* __restrict__ nb, float* __restrict__ qn, float* __restrict__ gnull)
{
    const int b = blockIdx.x, tid = threadIdx.x;
    __shared__ float qsh[D_];
    __shared__ float red[16];
    qsh[tid] = x[((size_t)b * L_ + (L_ - 1)) * D_ + tid];
    __syncthreads();
    const float* wrow = (tid < H_) ? (Wsem + (size_t)tid * D_)
                                   : (Wepi + (size_t)(tid - H_) * D_);
    float s = 0.f;
    for (int d = 0; d < D_; d += 4) {
        const float4 w4 = *(const float4*)(wrow + d);
        s += qsh[d]*w4.x + qsh[d+1]*w4.y + qsh[d+2]*w4.z + qsh[d+3]*w4.w;
    }
    float sq = s * s;
#pragma unroll
    for (int o = 32; o; o >>= 1) sq += __shfl_xor(sq, o);
    const int wid = tid >> 6, lane = tid & 63;
    if (lane == 0) red[wid] = sq;
    __syncthreads();
    float n2s = 0.f, n2e = 0.f;
#pragma unroll
    for (int i = 0; i < 8; ++i) { n2s += red[i]; n2e += red[i + 8]; }
    const float rns = 1.f / fmaxf(sqrtf(n2s), 1e-12f);
    const float rne = 1.f / fmaxf(sqrtf(n2e), 1e-12f);
    qn[(size_t)b * D_ + tid] = s * ((tid < H_) ? rns : rne);
    if (wid == 0) {
        float g = 0.f;
        for (int d = lane * 4; d < D_; d += 256) {
            const float4 w4 = *(const float4*)(nw + d);
            g += qsh[d]*w4.x + qsh[d+1]*w4.y + qsh[d+2]*w4.z + qsh[d+3]*w4.w;
        }
#pragma unroll
        for (int o = 32; o; o >>= 1) g += __shfl_xor(g, o);
        if (lane == 0) gnull[b] = 1.f / (1.f + expf(-(g + nb[0])));
    }
}

// ---------------------------------------------------------------------------
// rg[b][n] = gnull[b] * sum_j M[b][m][i][j] qn[b][m*512+j]   grid (16,256), block 256
// ---------------------------------------------------------------------------
__global__ void k_rmv(const float* __restrict__ M, const float* __restrict__ qn,
                      const float* __restrict__ gnull, float* __restrict__ rg)
{
    const int b = blockIdx.x;
    const int n = blockIdx.y * 4 + (threadIdx.x >> 6);
    const int lane = threadIdx.x & 63;
    const int m = n >> 9, i = n & 511;
    const float* Mr = M + ((size_t)(b*2+m) * H_ + i) * H_;
    const float* qv = qn + (size_t)b * D_ + m * H_;
    float s = 0.f;
#pragma unroll
    for (int it = 0; it < 2; ++it) {
        const int j = lane * 4 + it * 256;
        const float4 m4 = *(const float4*)(Mr + j);
        const float4 q4 = *(const float4*)(qv + j);
        s += m4.x*q4.x + m4.y*q4.y + m4.z*q4.z + m4.w*q4.w;
    }
#pragma unroll
    for (int o = 32; o; o >>= 1) s += __shfl_xor(s, o);
    if (lane == 0) rg[(size_t)b * D_ + n] = gnull[b] * s;
}

// ---------------------------------------------------------------------------
// out[b][o] = sum_d rg[b][d] * outw[o][d] + outb[o]        grid (16,256), block 256
// ---------------------------------------------------------------------------
__global__ void k_out(const float* __restrict__ rg, const float* __restrict__ outw,
                      const float* __restrict__ outb, float* __restrict__ out)
{
    const int b = blockIdx.x;
    const int o = blockIdx.y * 4 + (threadIdx.x >> 6);
    const int lane = threadIdx.x & 63;
    const float* wr = outw + (size_t)o * D_;
    const float* rv = rg + (size_t)b * D_;
    float s = 0.f;
#pragma unroll
    for (int it = 0; it < 4; ++it) {
        const int j = lane * 4 + it * 256;
        const float4 w4 = *(const float4*)(wr + j);
        const float4 r4 = *(const float4*)(rv + j);
        s += w4.x*r4.x + w4.y*r4.y + w4.z*r4.z + w4.w*r4.w;
    }
#pragma unroll
    for (int o2 = 32; o2; o2 >>= 1) s += __shfl_xor(s, o2);
    if (lane == 0) out[(size_t)b * D_ + o] = s + outb[o];
}

// ---------------------------------------------------------------------------
extern "C" void kernel_launch(void* const* d_in, const int* in_sizes, int n_in,
                              void* d_out, int out_size, void* d_ws, size_t ws_size,
                              hipStream_t stream)
{
    (void)in_sizes; (void)n_in; (void)out_size;
    const float* x     = (const float*)d_in[0];
    const float* Wsem  = (const float*)d_in[1];
    const float* Wepi  = (const float*)d_in[2];
    const float* nullw = (const float*)d_in[3];
    const float* nullb = (const float*)d_in[4];
    const float* outw  = (const float*)d_in[5];
    const float* outb  = (const float*)d_in[6];
    float* out = (float*)d_out;

    float* ws = (float*)d_ws;
    size_t off = 0;
    float* K     = ws + off; off += (size_t)B_ * LM1 * D_;
    float* nk2   = ws + off; off += (size_t)B_ * 2 * LM1;
    float* rn    = ws + off; off += (size_t)B_ * 2 * LM1;
    float* Mm    = ws + off; off += (size_t)B_ * 2 * H_ * H_;
    float* Vext  = ws + off; off += (size_t)B_ * 2 * TBLK * H_;
    float* G     = ws + off; off += (size_t)B_ * 2 * NBLK * TBLK * TBLK;
    float* AU    = ws + off; off += (size_t)B_ * 2 * TBLK * H_;
    float* qn    = ws + off; off += (size_t)B_ * D_;
    float* gnull = ws + off; off += (size_t)B_;
    float* rg    = ws + off; off += (size_t)B_ * D_;
    if (ws_size < off * sizeof(float)) return;   // insufficient scratch -> fail loudly

    float omA = (float)(1.0 - pow(0.95, 96.0 / 2048.0));

    k_proj <<<dim3(512, 16), 256, 0, stream>>>(x, Wsem, Wepi, K);
    k_norms<<<dim3(B_ * LM1), 256, 0, stream>>>(K, nk2, rn);
    k_gram <<<dim3(NBLK, B_ * 2), 256, 0, stream>>>(K, rn, G);

    {
        void* args[] = { (void*)&K, (void*)&rn, (void*)&nk2, (void*)&G,
                         (void*)&Mm, (void*)&Vext, (void*)&AU, (void*)&omA };
        hipLaunchCooperativeKernel((void*)k_scan, dim3(NWG), dim3(1024), args, 0, stream);
    }

    k_q  <<<dim3(B_), 1024, 0, stream>>>(x, Wsem, Wepi, nullw, nullb, qn, gnull);
    k_rmv<<<dim3(16, 256), 256, 0, stream>>>(Mm, qn, gnull, rg);
    k_out<<<dim3(16, 256), 256, 0, stream>>>(rg, outw, outb, out);
}

// Round 7
// 15449.745 us; speedup vs baseline: 14.0569x; 14.0569x over previous
//
#include <hip/hip_runtime.h>
#include <math.h>

#define B_    16
#define L_    2048
#define LM1   2047
#define D_    1024
#define H_    512
#define TB    40
#define NBLK  52    // 52*40 = 2080 >= 2047
#define NWG   256

// ---------------------------------------------------------------------------
// lean grid barrier (semantics validated round 6: absmax 7.6e-6 passed)
// ---------------------------------------------------------------------------
__device__ int g_bar[2] = {0, 0};

__device__ __forceinline__ void gbar()
{
    __syncthreads();
    if (threadIdx.x == 0) {
        __threadfence();
        int* cnt = &g_bar[0];
        int* gen = &g_bar[1];
        const int g = __hip_atomic_load(gen, __ATOMIC_ACQUIRE, __HIP_MEMORY_SCOPE_AGENT);
        if (__hip_atomic_fetch_add(cnt, 1, __ATOMIC_ACQ_REL, __HIP_MEMORY_SCOPE_AGENT) == NWG - 1) {
            __hip_atomic_store(cnt, 0, __ATOMIC_RELAXED, __HIP_MEMORY_SCOPE_AGENT);
            __hip_atomic_store(gen, g + 1, __ATOMIC_RELEASE, __HIP_MEMORY_SCOPE_AGENT);
        } else {
            while (__hip_atomic_load(gen, __ATOMIC_ACQUIRE, __HIP_MEMORY_SCOPE_AGENT) == g)
                __builtin_amdgcn_s_sleep(2);
        }
        __threadfence();
    }
    __syncthreads();
}

// ---------------------------------------------------------------------------
// K[r][n] = sum_d x[b*L+t][d] * Wcat[n][d]   grid (512,16), block 256
// ---------------------------------------------------------------------------
__global__ void k_proj(const float* __restrict__ x, const float* __restrict__ Wsem,
                       const float* __restrict__ Wepi, float* __restrict__ K)
{
    __shared__ float As[16][68];
    __shared__ float Bs[16][68];
    const int tid = threadIdx.x;
    const int tx = tid & 15, ty = tid >> 4;
    const int r0 = blockIdx.x * 64;
    const int n0 = blockIdx.y * 64;
    const int lr  = tid >> 2;
    const int lk4 = (tid & 3) << 2;
    const int rowg = r0 + lr;
    const bool rok = rowg < B_ * LM1;
    const int rowc = rok ? rowg : 0;
    const int bb = rowc / LM1;
    const int tt = rowc - bb * LM1;
    const float* xrow = x + ((size_t)bb * L_ + tt) * D_;
    const int nW = n0 + lr;
    const float* wrow = (nW < H_) ? (Wsem + (size_t)nW * D_)
                                  : (Wepi + (size_t)(nW - H_) * D_);
    float acc[4][4];
#pragma unroll
    for (int i = 0; i < 4; ++i)
#pragma unroll
        for (int j = 0; j < 4; ++j) acc[i][j] = 0.f;

    for (int kk = 0; kk < D_; kk += 16) {
        const float4 av = rok ? *(const float4*)(xrow + kk + lk4) : make_float4(0.f,0.f,0.f,0.f);
        const float4 bv = *(const float4*)(wrow + kk + lk4);
        As[lk4+0][lr] = av.x; As[lk4+1][lr] = av.y; As[lk4+2][lr] = av.z; As[lk4+3][lr] = av.w;
        Bs[lk4+0][lr] = bv.x; Bs[lk4+1][lr] = bv.y; Bs[lk4+2][lr] = bv.z; Bs[lk4+3][lr] = bv.w;
        __syncthreads();
#pragma unroll
        for (int k = 0; k < 16; ++k) {
            const float4 a4 = *(const float4*)&As[k][ty << 2];
            const float4 b4 = *(const float4*)&Bs[k][tx << 2];
            const float aa[4] = {a4.x, a4.y, a4.z, a4.w};
            const float bbv[4] = {b4.x, b4.y, b4.z, b4.w};
#pragma unroll
            for (int i = 0; i < 4; ++i)
#pragma unroll
                for (int j = 0; j < 4; ++j)
                    acc[i][j] = fmaf(aa[i], bbv[j], acc[i][j]);
        }
        __syncthreads();
    }
#pragma unroll
    for (int i = 0; i < 4; ++i) {
        const int r = r0 + (ty << 2) + i;
        if (r < B_ * LM1)
            *(float4*)(K + (size_t)r * D_ + n0 + (tx << 2)) =
                make_float4(acc[i][0], acc[i][1], acc[i][2], acc[i][3]);
    }
}

// ---------------------------------------------------------------------------
// norms.  grid B_*LM1, block 256
// ---------------------------------------------------------------------------
__global__ void k_norms(const float* __restrict__ K, float* __restrict__ nk2,
                        float* __restrict__ rn)
{
    const int r = blockIdx.x;
    const int tid = threadIdx.x;
    const float4 v = *(const float4*)(K + (size_t)r * D_ + (tid << 2));
    float s = v.x*v.x + v.y*v.y + v.z*v.z + v.w*v.w;
#pragma unroll
    for (int o = 32; o; o >>= 1) s += __shfl_xor(s, o);
    __shared__ float part[4];
    const int wid = tid >> 6, lane = tid & 63;
    if (lane == 0) part[wid] = s;
    __syncthreads();
    if (tid == 0) {
        const int b = r / LM1, t = r - b * LM1;
        const float s0 = part[0] + part[1];
        const float s1 = part[2] + part[3];
        nk2[(size_t)(b*2+0)*LM1 + t] = s0;
        nk2[(size_t)(b*2+1)*LM1 + t] = s1;
        rn [(size_t)(b*2+0)*LM1 + t] = 1.f / fmaxf(sqrtf(s0), 1e-12f);
        rn [(size_t)(b*2+1)*LM1 + t] = 1.f / fmaxf(sqrtf(s1), 1e-12f);
    }
}

// ---------------------------------------------------------------------------
// Gram, shifted layout: G[bm][blk][t*TB+d] = kn_t . kn_{t+d}, 0 if OOB.
// grid (NBLK, 32), block 256.  LDS-chunked over columns (21 KB static).
// ---------------------------------------------------------------------------
__global__ void k_gram(const float* __restrict__ K, const float* __restrict__ rn,
                       float* __restrict__ G)
{
    __shared__ float rows[TB * 129];
    const int blk = blockIdx.x, bm = blockIdx.y;
    const int b = bm >> 1, m = bm & 1;
    const int t0 = blk * TB;
    const int Tb = (LM1 - t0 < TB) ? (LM1 - t0) : TB;
    const int tid = threadIdx.x;

    float acc[7];
#pragma unroll
    for (int e = 0; e < 7; ++e) acc[e] = 0.f;

    for (int c0 = 0; c0 < H_; c0 += 128) {
        for (int v = tid; v < TB * 128; v += 256) {
            const int t = v >> 7, c = v & 127;
            float val = 0.f;
            if (t < Tb)
                val = K[((size_t)(b * LM1 + t0 + t)) * D_ + m * H_ + c0 + c]
                    * rn[(size_t)bm * LM1 + t0 + t];
            rows[t * 129 + c] = val;
        }
        __syncthreads();
        for (int e = 0; e < 7; ++e) {
            const int idx = e * 256 + tid;
            if (idx < TB * TB) {
                const int t = idx / TB, d = idx - t * TB;
                if (t + d < Tb) {
                    const float* ra = rows + t * 129;
                    const float* rb = rows + (t + d) * 129;
                    float s = acc[e];
                    for (int c = 0; c < 128; ++c) s = fmaf(ra[c], rb[c], s);
                    acc[e] = s;
                }
            }
        }
        __syncthreads();
    }
    float* Gout = G + ((size_t)bm * NBLK + blk) * (TB * TB);
    for (int e = 0; e < 7; ++e) {
        const int idx = e * 256 + tid;
        if (idx < TB * TB) {
            const int t = idx / TB, d = idx - t * TB;
            Gout[idx] = (t + d < Tb) ? acc[e] : 0.f;
        }
    }
}

// pending-shift chunk: pA..pD updated from g with coefficient vvx
#define CH4(g,vvx,pA,pB,pC,pD,pE) \
    pA = fmaf(g.x, vvx, pB); pB = fmaf(g.y, vvx, pC); \
    pC = fmaf(g.z, vvx, pD); pD = fmaf(g.w, vvx, pE);

// ---------------------------------------------------------------------------
// Fused scan.  256 WGs x 512 threads (512-thr: compiler allocates ~108-128
// VGPR, rounds 2/3 measured).  WG w owns M-slab (bm=w>>3, rows i0=(w&7)*64):
// A and C touch ONLY the own slab -> C(blk-1);A(blk) need no barrier between.
// Phase B (WGs 0..15): TB=40 -> p[40]x2 = 80 named scalars, ~110 VGPR total.
// ---------------------------------------------------------------------------
__global__ void __launch_bounds__(512, 2) k_scan(
    const float* __restrict__ K, const float* __restrict__ rn,
    const float* __restrict__ nk2, const float* __restrict__ G,
    float* __restrict__ Mm, float* __restrict__ Vext, float* __restrict__ AU,
    float omA)
{
    const int wg  = blockIdx.x;
    const int tid = threadIdx.x;
    __shared__ float sh[5440];
    __shared__ float part[32];
    __shared__ float rnsh[TB];

    const int bm = wg >> 3;
    const int i0 = (wg & 7) << 6;
    const int b  = bm >> 1, m = bm & 1;

    // zero own slab (contiguous 64x512 floats)
    {
        float4* M4 = (float4*)(Mm + ((size_t)bm * H_ + i0) * H_);
        for (int v = tid; v < (64 * H_) / 4; v += 512)
            M4[v] = make_float4(0.f, 0.f, 0.f, 0.f);
    }

    for (int blk = 0; blk <= NBLK; ++blk) {
        // ================= Phase C for blk-1 (own slab M += vv^T kn) ========
        if (blk > 0) {
            const int ct0 = (blk - 1) * TB;
            const int cTb = (LM1 - ct0 < TB) ? (LM1 - ct0) : TB;
            __syncthreads();
            if (tid < TB) rnsh[tid] = (tid < cTb) ? rn[(size_t)bm * LM1 + ct0 + tid] : 0.f;
            // stage AUs[t][i] once  (sh[0..2720))
            for (int v = tid; v < TB * 64; v += 512) {
                const int t = v >> 6, i2 = v & 63;
                sh[t * 68 + i2] = (t < cTb) ? AU[((size_t)bm * TB + t) * H_ + i0 + i2] : 0.f;
            }
            __syncthreads();
            const int j  = tid & 63;
            const int ig = tid >> 6;
            for (int jch = 0; jch < 8; ++jch) {
                const int j0 = jch << 6;
                for (int v = tid; v < TB * 64; v += 512) {
                    const int t = v >> 6, jj = v & 63;
                    sh[2720 + t * 68 + jj] = (t < cTb)
                        ? K[((size_t)(b * LM1 + ct0 + t)) * D_ + m * H_ + j0 + jj] * rnsh[t]
                        : 0.f;
                }
                __syncthreads();
                float acc[8];
#pragma unroll
                for (int q = 0; q < 8; ++q) acc[q] = 0.f;
                for (int t = 0; t < TB; ++t) {
                    const float kv = sh[2720 + t * 68 + j];
#pragma unroll
                    for (int q = 0; q < 8; ++q)
                        acc[q] = fmaf(sh[t * 68 + ig + (q << 3)], kv, acc[q]);
                }
#pragma unroll
                for (int q = 0; q < 8; ++q) {
                    float* p = Mm + ((size_t)bm * H_ + i0 + ig + (q << 3)) * H_ + j0 + j;
                    *p += acc[q];
                }
                __syncthreads();
            }
        }

        if (blk < NBLK) {
            const int t0 = blk * TB;
            const int Tb = (LM1 - t0 < TB) ? (LM1 - t0) : TB;

            // ================= Phase A: Vext = rn o (K_blk @ Mslab^T) ========
            {
                __syncthreads();
                if (tid < TB) rnsh[tid] = (tid < Tb) ? rn[(size_t)bm * LM1 + t0 + tid] : 0.f;
                __syncthreads();
                const int i  = tid & 63;
                const int tg = tid >> 6;
                float acc[5];
#pragma unroll
                for (int q = 0; q < 5; ++q) acc[q] = 0.f;
                for (int jch = 0; jch < 32; ++jch) {
                    const int j0 = jch << 4;
                    // Mt[64][17]  (sh[0..1088))
                    for (int v = tid; v < 1024; v += 512) {
                        const int i2 = v >> 4, jc = v & 15;
                        sh[i2 * 17 + jc] = Mm[((size_t)bm * H_ + i0 + i2) * H_ + j0 + jc];
                    }
                    // Ks[jc][44] transposed  (sh[1088..1792))
                    for (int v = tid; v < TB * 16; v += 512) {
                        const int t2 = v >> 4, jc = v & 15;
                        sh[1088 + jc * 44 + t2] = (t2 < Tb)
                            ? K[((size_t)(b * LM1 + t0 + t2)) * D_ + m * H_ + j0 + jc] * rnsh[t2]
                            : 0.f;
                    }
                    __syncthreads();
#pragma unroll
                    for (int jc = 0; jc < 16; ++jc) {
                        const float mv = sh[i * 17 + jc];
#pragma unroll
                        for (int q = 0; q < 5; ++q)
                            acc[q] = fmaf(mv, sh[1088 + jc * 44 + tg + (q << 3)], acc[q]);
                    }
                    __syncthreads();
                }
#pragma unroll
                for (int q = 0; q < 5; ++q) {
                    const int t = tg + (q << 3);
                    if (t < Tb)
                        Vext[((size_t)bm * TB + t) * H_ + i0 + i] = acc[q];
                }
            }
            gbar();   // Vext ready

            // ================= Phase B (WGs 0..15): sequential scan ==========
            if (wg < B_) {
                const int bq = wg;
                const int wid = tid >> 6, lane = tid & 63;
                {
                    const float4* g0 = (const float4*)(G + ((size_t)(bq*2+0) * NBLK + blk) * (TB*TB));
                    const float4* g1 = (const float4*)(G + ((size_t)(bq*2+1) * NBLK + blk) * (TB*TB));
                    if (tid < 400) {
                        ((float4*)sh)[tid]       = g0[tid];
                        ((float4*)sh)[400 + tid] = g1[tid];
                    }
                }
                float p00=0.f,p01=0.f,p02=0.f,p03=0.f,p04=0.f,p05=0.f,p06=0.f,p07=0.f;
                float p08=0.f,p09=0.f,p10=0.f,p11=0.f,p12=0.f,p13=0.f,p14=0.f,p15=0.f;
                float p16=0.f,p17=0.f,p18=0.f,p19=0.f,p20=0.f,p21=0.f,p22=0.f,p23=0.f;
                float p24=0.f,p25=0.f,p26=0.f,p27=0.f,p28=0.f,p29=0.f,p30=0.f,p31=0.f;
                float p32=0.f,p33=0.f,p34=0.f,p35=0.f,p36=0.f,p37=0.f,p38=0.f,p39=0.f;
                float q00=0.f,q01=0.f,q02=0.f,q03=0.f,q04=0.f,q05=0.f,q06=0.f,q07=0.f;
                float q08=0.f,q09=0.f,q10=0.f,q11=0.f,q12=0.f,q13=0.f,q14=0.f,q15=0.f;
                float q16=0.f,q17=0.f,q18=0.f,q19=0.f,q20=0.f,q21=0.f,q22=0.f,q23=0.f;
                float q24=0.f,q25=0.f,q26=0.f,q27=0.f,q28=0.f,q29=0.f,q30=0.f,q31=0.f;
                float q32=0.f,q33=0.f,q34=0.f,q35=0.f,q36=0.f,q37=0.f,q38=0.f,q39=0.f;
                __syncthreads();

                const float* Kb0 = K + ((size_t)(bq * LM1 + t0)) * D_ + tid;
                const float* Kb1 = Kb0 + H_;
                const float* Vb0 = Vext + ((size_t)(bq*2+0) * TB) * H_ + tid;
                const float* Vb1 = Vext + ((size_t)(bq*2+1) * TB) * H_ + tid;
                float* AU0 = AU + ((size_t)(bq*2+0) * TB) * H_ + tid;
                float* AU1 = AU + ((size_t)(bq*2+1) * TB) * H_ + tid;
                const float* qs = nk2 + (size_t)(bq*2+0) * LM1 + t0;
                const float* qe = nk2 + (size_t)(bq*2+1) * LM1 + t0;

                float kc0 = Kb0[0], kc1 = Kb1[0], vc0 = Vb0[0], vc1 = Vb1[0];
                float ncs = qs[0],  nce = qe[0];

                for (int t = 0; t < Tb; ++t) {
                    const float u0 = kc0 - vc0 - p00;
                    const float u1 = kc1 - vc1 - q00;
                    float kn0=0.f, kn1=0.f, vn0=0.f, vn1=0.f, nns=0.f, nne=0.f;
                    if (t + 1 < Tb) {
                        kn0 = Kb0[(size_t)(t+1) * D_]; kn1 = Kb1[(size_t)(t+1) * D_];
                        vn0 = Vb0[(t+1) * H_];         vn1 = Vb1[(t+1) * H_];
                        nns = qs[t+1];                 nne = qe[t+1];
                    }
                    float s0 = u0 * u0, s1 = u1 * u1;
#pragma unroll
                    for (int o = 32; o; o >>= 1) { s0 += __shfl_xor(s0, o); s1 += __shfl_xor(s1, o); }
                    float* pp = &part[(t & 1) << 4];
                    if (lane == 0) { pp[wid] = s0; pp[wid + 8] = s1; }
                    asm volatile("s_waitcnt lgkmcnt(0)" ::: "memory");
                    __builtin_amdgcn_s_barrier();
                    __builtin_amdgcn_sched_barrier(0);
                    float Ns = 0.f, Ne = 0.f;
#pragma unroll
                    for (int i = 0; i < 8; ++i) { Ns += pp[i]; Ne += pp[i + 8]; }
                    const bool fire = (Ns >= 0.49f * ncs) || (Ne >= 0.49f * nce);
                    const float w = (float)(t0 + t + 1) * (1.0f / (float)L_);
                    const float vv0 = fire ? omA * u0 : 0.f;
                    const float vv1 = fire ? omA * w * u1 : 0.f;
                    AU0[(size_t)t * H_] = vv0;
                    AU1[(size_t)t * H_] = vv1;

                    const float4* Gr0 = (const float4*)(sh + t * TB);
                    const float4* Gr1 = (const float4*)(sh + 1600 + t * TB);
                    float4 g;
                    g = Gr0[0];
                    p00 = fmaf(g.y, vv0, p01); p01 = fmaf(g.z, vv0, p02); p02 = fmaf(g.w, vv0, p03);
                    g = Gr0[1]; CH4(g, vv0, p03,p04,p05,p06,p07)
                    g = Gr0[2]; CH4(g, vv0, p07,p08,p09,p10,p11)
                    g = Gr0[3]; CH4(g, vv0, p11,p12,p13,p14,p15)
                    g = Gr0[4]; CH4(g, vv0, p15,p16,p17,p18,p19)
                    g = Gr0[5]; CH4(g, vv0, p19,p20,p21,p22,p23)
                    g = Gr0[6]; CH4(g, vv0, p23,p24,p25,p26,p27)
                    g = Gr0[7]; CH4(g, vv0, p27,p28,p29,p30,p31)
                    g = Gr0[8]; CH4(g, vv0, p31,p32,p33,p34,p35)
                    g = Gr0[9]; CH4(g, vv0, p35,p36,p37,p38,p39)
                    p39 = 0.f;
                    g = Gr1[0];
                    q00 = fmaf(g.y, vv1, q01); q01 = fmaf(g.z, vv1, q02); q02 = fmaf(g.w, vv1, q03);
                    g = Gr1[1]; CH4(g, vv1, q03,q04,q05,q06,q07)
                    g = Gr1[2]; CH4(g, vv1, q07,q08,q09,q10,q11)
                    g = Gr1[3]; CH4(g, vv1, q11,q12,q13,q14,q15)
                    g = Gr1[4]; CH4(g, vv1, q15,q16,q17,q18,q19)
                    g = Gr1[5]; CH4(g, vv1, q19,q20,q21,q22,q23)
                    g = Gr1[6]; CH4(g, vv1, q23,q24,q25,q26,q27)
                    g = Gr1[7]; CH4(g, vv1, q27,q28,q29,q30,q31)
                    g = Gr1[8]; CH4(g, vv1, q31,q32,q33,q34,q35)
                    g = Gr1[9]; CH4(g, vv1, q35,q36,q37,q38,q39)
                    q39 = 0.f;

                    kc0 = kn0; kc1 = kn1; vc0 = vn0; vc1 = vn1; ncs = nns; nce = nne;
                }
            }
            gbar();   // AU ready
        }
    }
}

// ---------------------------------------------------------------------------
// query path.  grid B_, block 1024
// ---------------------------------------------------------------------------
__global__ void __launch_bounds__(1024) k_q(
    const float* __restrict__ x, const float* __restrict__ Wsem,
    const float* __restrict__ Wepi, const float* __restrict__ nw,
    const float* __restrict__ nb, float* __restrict__ qn, float* __restrict__ gnull)
{
    const int b = blockIdx.x, tid = threadIdx.x;
    __shared__ float qsh[D_];
    __shared__ float red[16];
    qsh[tid] = x[((size_t)b * L_ + (L_ - 1)) * D_ + tid];
    __syncthreads();
    const float* wrow = (tid < H_) ? (Wsem + (size_t)tid * D_)
                                   : (Wepi + (size_t)(tid - H_) * D_);
    float s = 0.f;
    for (int d = 0; d < D_; d += 4) {
        const float4 w4 = *(const float4*)(wrow + d);
        s += qsh[d]*w4.x + qsh[d+1]*w4.y + qsh[d+2]*w4.z + qsh[d+3]*w4.w;
    }
    float sq = s * s;
#pragma unroll
    for (int o = 32; o; o >>= 1) sq += __shfl_xor(sq, o);
    const int wid = tid >> 6, lane = tid & 63;
    if (lane == 0) red[wid] = sq;
    __syncthreads();
    float n2s = 0.f, n2e = 0.f;
#pragma unroll
    for (int i = 0; i < 8; ++i) { n2s += red[i]; n2e += red[i + 8]; }
    const float rns = 1.f / fmaxf(sqrtf(n2s), 1e-12f);
    const float rne = 1.f / fmaxf(sqrtf(n2e), 1e-12f);
    qn[(size_t)b * D_ + tid] = s * ((tid < H_) ? rns : rne);
    if (wid == 0) {
        float g = 0.f;
        for (int d = lane * 4; d < D_; d += 256) {
            const float4 w4 = *(const float4*)(nw + d);
            g += qsh[d]*w4.x + qsh[d+1]*w4.y + qsh[d+2]*w4.z + qsh[d+3]*w4.w;
        }
#pragma unroll
        for (int o = 32; o; o >>= 1) g += __shfl_xor(g, o);
        if (lane == 0) gnull[b] = 1.f / (1.f + expf(-(g + nb[0])));
    }
}

// ---------------------------------------------------------------------------
__global__ void k_rmv(const float* __restrict__ M, const float* __restrict__ qn,
                      const float* __restrict__ gnull, float* __restrict__ rg)
{
    const int b = blockIdx.x;
    const int n = blockIdx.y * 4 + (threadIdx.x >> 6);
    const int lane = threadIdx.x & 63;
    const int m = n >> 9, i = n & 511;
    const float* Mr = M + ((size_t)(b*2+m) * H_ + i) * H_;
    const float* qv = qn + (size_t)b * D_ + m * H_;
    float s = 0.f;
#pragma unroll
    for (int it = 0; it < 2; ++it) {
        const int j = lane * 4 + it * 256;
        const float4 m4 = *(const float4*)(Mr + j);
        const float4 q4 = *(const float4*)(qv + j);
        s += m4.x*q4.x + m4.y*q4.y + m4.z*q4.z + m4.w*q4.w;
    }
#pragma unroll
    for (int o = 32; o; o >>= 1) s += __shfl_xor(s, o);
    if (lane == 0) rg[(size_t)b * D_ + n] = gnull[b] * s;
}

// ---------------------------------------------------------------------------
__global__ void k_out(const float* __restrict__ rg, const float* __restrict__ outw,
                      const float* __restrict__ outb, float* __restrict__ out)
{
    const int b = blockIdx.x;
    const int o = blockIdx.y * 4 + (threadIdx.x >> 6);
    const int lane = threadIdx.x & 63;
    const float* wr = outw + (size_t)o * D_;
    const float* rv = rg + (size_t)b * D_;
    float s = 0.f;
#pragma unroll
    for (int it = 0; it < 4; ++it) {
        const int j = lane * 4 + it * 256;
        const float4 w4 = *(const float4*)(wr + j);
        const float4 r4 = *(const float4*)(rv + j);
        s += w4.x*r4.x + w4.y*r4.y + w4.z*r4.z + w4.w*r4.w;
    }
#pragma unroll
    for (int o2 = 32; o2; o2 >>= 1) s += __shfl_xor(s, o2);
    if (lane == 0) out[(size_t)b * D_ + o] = s + outb[o];
}

// ---------------------------------------------------------------------------
extern "C" void kernel_launch(void* const* d_in, const int* in_sizes, int n_in,
                              void* d_out, int out_size, void* d_ws, size_t ws_size,
                              hipStream_t stream)
{
    (void)in_sizes; (void)n_in; (void)out_size;
    const float* x     = (const float*)d_in[0];
    const float* Wsem  = (const float*)d_in[1];
    const float* Wepi  = (const float*)d_in[2];
    const float* nullw = (const float*)d_in[3];
    const float* nullb = (const float*)d_in[4];
    const float* outw  = (const float*)d_in[5];
    const float* outb  = (const float*)d_in[6];
    float* out = (float*)d_out;

    float* ws = (float*)d_ws;
    size_t off = 0;
    float* K     = ws + off; off += (size_t)B_ * LM1 * D_;
    float* nk2   = ws + off; off += (size_t)B_ * 2 * LM1;
    float* rn    = ws + off; off += (size_t)B_ * 2 * LM1;
    float* Mm    = ws + off; off += (size_t)B_ * 2 * H_ * H_;
    float* Vext  = ws + off; off += (size_t)B_ * 2 * TB * H_;
    float* G     = ws + off; off += (size_t)B_ * 2 * NBLK * TB * TB;
    float* AU    = ws + off; off += (size_t)B_ * 2 * TB * H_;
    float* qn    = ws + off; off += (size_t)B_ * D_;
    float* gnull = ws + off; off += (size_t)B_;
    float* rg    = ws + off; off += (size_t)B_ * D_;
    if (ws_size < off * sizeof(float)) return;

    float omA = (float)(1.0 - pow(0.95, 96.0 / 2048.0));

    k_proj <<<dim3(512, 16), 256, 0, stream>>>(x, Wsem, Wepi, K);
    k_norms<<<dim3(B_ * LM1), 256, 0, stream>>>(K, nk2, rn);
    k_gram <<<dim3(NBLK, B_ * 2), 256, 0, stream>>>(K, rn, G);

    {
        void* args[] = { (void*)&K, (void*)&rn, (void*)&nk2, (void*)&G,
                         (void*)&Mm, (void*)&Vext, (void*)&AU, (void*)&omA };
        hipLaunchCooperativeKernel((void*)k_scan, dim3(NWG), dim3(512), args, 0, stream);
    }

    k_q  <<<dim3(B_), 1024, 0, stream>>>(x, Wsem, Wepi, nullw, nullb, qn, gnull);
    k_rmv<<<dim3(16, 256), 256, 0, stream>>>(Mm, qn, gnull, rg);
    k_out<<<dim3(16, 256), 256, 0, stream>>>(rg, outw, outb, out);
}

// Round 9
// 10402.691 us; speedup vs baseline: 20.8768x; 1.4852x over previous
//
#include <hip/hip_runtime.h>
#include <math.h>

#define B_    16
#define L_    2048
#define LM1   2047
#define D_    1024
#define H_    512
#define TB    40
#define NBLK  52    // 52*40 = 2080 >= 2047
#define NWG   256

// ---------------------------------------------------------------------------
// Deadlock-proof lean grid barrier (round 9).
//  * monotonic counter in d_ws (memset to 0 each launch) -> no reset race
//    (round 8's relaxed cnt-reset/gen-bump pair could reorder -> deadlock)
//  * arrival: relaxed agent fetch_add (RMW executes at coherence point)
//  * poll: global_load sc0 sc1 = coherent read, NO invalidate side effect
//    (round 7's acquire-per-poll emitted buffer_inv each iteration -> L2
//     wiped continuously -> M streamed from HBM -> 14.3 ms)
//  * one release fence (wb) before arrival, one acquire fence (inv) after.
// ---------------------------------------------------------------------------
__device__ __forceinline__ unsigned int bar_poll(const unsigned int* p)
{
    unsigned int v;
    asm volatile("global_load_dword %0, %1, off sc0 sc1\n\t"
                 "s_waitcnt vmcnt(0)"
                 : "=v"(v) : "v"(p) : "memory");
    return v;
}

__device__ __forceinline__ void gbar(unsigned int* bar, unsigned int& ep)
{
    __syncthreads();
    if (threadIdx.x == 0) {
        __builtin_amdgcn_fence(__ATOMIC_RELEASE, "agent");   // wb dirty L2 once
        ep += NWG;
        __hip_atomic_fetch_add(bar, 1u, __ATOMIC_RELAXED, __HIP_MEMORY_SCOPE_AGENT);
        while (bar_poll(bar) < ep)
            __builtin_amdgcn_s_sleep(16);
        __builtin_amdgcn_fence(__ATOMIC_ACQUIRE, "agent");   // inv stale L2 once
    }
    __syncthreads();
}

// ---------------------------------------------------------------------------
// K[r][n] = sum_d x[b*L+t][d] * Wcat[n][d]   grid (512,16), block 256
// ---------------------------------------------------------------------------
__global__ void k_proj(const float* __restrict__ x, const float* __restrict__ Wsem,
                       const float* __restrict__ Wepi, float* __restrict__ K)
{
    __shared__ float As[16][68];
    __shared__ float Bs[16][68];
    const int tid = threadIdx.x;
    const int tx = tid & 15, ty = tid >> 4;
    const int r0 = blockIdx.x * 64;
    const int n0 = blockIdx.y * 64;
    const int lr  = tid >> 2;
    const int lk4 = (tid & 3) << 2;
    const int rowg = r0 + lr;
    const bool rok = rowg < B_ * LM1;
    const int rowc = rok ? rowg : 0;
    const int bb = rowc / LM1;
    const int tt = rowc - bb * LM1;
    const float* xrow = x + ((size_t)bb * L_ + tt) * D_;
    const int nW = n0 + lr;
    const float* wrow = (nW < H_) ? (Wsem + (size_t)nW * D_)
                                  : (Wepi + (size_t)(nW - H_) * D_);
    float acc[4][4];
#pragma unroll
    for (int i = 0; i < 4; ++i)
#pragma unroll
        for (int j = 0; j < 4; ++j) acc[i][j] = 0.f;

    for (int kk = 0; kk < D_; kk += 16) {
        const float4 av = rok ? *(const float4*)(xrow + kk + lk4) : make_float4(0.f,0.f,0.f,0.f);
        const float4 bv = *(const float4*)(wrow + kk + lk4);
        As[lk4+0][lr] = av.x; As[lk4+1][lr] = av.y; As[lk4+2][lr] = av.z; As[lk4+3][lr] = av.w;
        Bs[lk4+0][lr] = bv.x; Bs[lk4+1][lr] = bv.y; Bs[lk4+2][lr] = bv.z; Bs[lk4+3][lr] = bv.w;
        __syncthreads();
#pragma unroll
        for (int k = 0; k < 16; ++k) {
            const float4 a4 = *(const float4*)&As[k][ty << 2];
            const float4 b4 = *(const float4*)&Bs[k][tx << 2];
            const float aa[4] = {a4.x, a4.y, a4.z, a4.w};
            const float bbv[4] = {b4.x, b4.y, b4.z, b4.w};
#pragma unroll
            for (int i = 0; i < 4; ++i)
#pragma unroll
                for (int j = 0; j < 4; ++j)
                    acc[i][j] = fmaf(aa[i], bbv[j], acc[i][j]);
        }
        __syncthreads();
    }
#pragma unroll
    for (int i = 0; i < 4; ++i) {
        const int r = r0 + (ty << 2) + i;
        if (r < B_ * LM1)
            *(float4*)(K + (size_t)r * D_ + n0 + (tx << 2)) =
                make_float4(acc[i][0], acc[i][1], acc[i][2], acc[i][3]);
    }
}

// ---------------------------------------------------------------------------
// norms.  grid B_*LM1, block 256
// ---------------------------------------------------------------------------
__global__ void k_norms(const float* __restrict__ K, float* __restrict__ nk2,
                        float* __restrict__ rn)
{
    const int r = blockIdx.x;
    const int tid = threadIdx.x;
    const float4 v = *(const float4*)(K + (size_t)r * D_ + (tid << 2));
    float s = v.x*v.x + v.y*v.y + v.z*v.z + v.w*v.w;
#pragma unroll
    for (int o = 32; o; o >>= 1) s += __shfl_xor(s, o);
    __shared__ float part[4];
    const int wid = tid >> 6, lane = tid & 63;
    if (lane == 0) part[wid] = s;
    __syncthreads();
    if (tid == 0) {
        const int b = r / LM1, t = r - b * LM1;
        const float s0 = part[0] + part[1];
        const float s1 = part[2] + part[3];
        nk2[(size_t)(b*2+0)*LM1 + t] = s0;
        nk2[(size_t)(b*2+1)*LM1 + t] = s1;
        rn [(size_t)(b*2+0)*LM1 + t] = 1.f / fmaxf(sqrtf(s0), 1e-12f);
        rn [(size_t)(b*2+1)*LM1 + t] = 1.f / fmaxf(sqrtf(s1), 1e-12f);
    }
}

// ---------------------------------------------------------------------------
// Gram, shifted layout: G[bm][blk][t*TB+d] = kn_t . kn_{t+d}, 0 if OOB.
// grid (NBLK, 32), block 256.
// ---------------------------------------------------------------------------
__global__ void k_gram(const float* __restrict__ K, const float* __restrict__ rn,
                       float* __restrict__ G)
{
    __shared__ float rows[TB * 129];
    const int blk = blockIdx.x, bm = blockIdx.y;
    const int b = bm >> 1, m = bm & 1;
    const int t0 = blk * TB;
    const int Tb = (LM1 - t0 < TB) ? (LM1 - t0) : TB;
    const int tid = threadIdx.x;

    float acc[7];
#pragma unroll
    for (int e = 0; e < 7; ++e) acc[e] = 0.f;

    for (int c0 = 0; c0 < H_; c0 += 128) {
        for (int v = tid; v < TB * 128; v += 256) {
            const int t = v >> 7, c = v & 127;
            float val = 0.f;
            if (t < Tb)
                val = K[((size_t)(b * LM1 + t0 + t)) * D_ + m * H_ + c0 + c]
                    * rn[(size_t)bm * LM1 + t0 + t];
            rows[t * 129 + c] = val;
        }
        __syncthreads();
        for (int e = 0; e < 7; ++e) {
            const int idx = e * 256 + tid;
            if (idx < TB * TB) {
                const int t = idx / TB, d = idx - t * TB;
                if (t + d < Tb) {
                    const float* ra = rows + t * 129;
                    const float* rb = rows + (t + d) * 129;
                    float s = acc[e];
                    for (int c = 0; c < 128; ++c) s = fmaf(ra[c], rb[c], s);
                    acc[e] = s;
                }
            }
        }
        __syncthreads();
    }
    float* Gout = G + ((size_t)bm * NBLK + blk) * (TB * TB);
    for (int e = 0; e < 7; ++e) {
        const int idx = e * 256 + tid;
        if (idx < TB * TB) {
            const int t = idx / TB, d = idx - t * TB;
            Gout[idx] = (t + d < Tb) ? acc[e] : 0.f;
        }
    }
}

// pending-shift chunk
#define CH4(g,vvx,pA,pB,pC,pD,pE) \
    pA = fmaf(g.x, vvx, pB); pB = fmaf(g.y, vvx, pC); \
    pC = fmaf(g.z, vvx, pD); pD = fmaf(g.w, vvx, pE);

// ---------------------------------------------------------------------------
// Fused scan (round-7 structure, VGPR=96 verified; only gbar changed).
// ---------------------------------------------------------------------------
__global__ void __launch_bounds__(512, 2) k_scan(
    const float* __restrict__ K, const float* __restrict__ rn,
    const float* __restrict__ nk2, const float* __restrict__ G,
    float* __restrict__ Mm, float* __restrict__ Vext, float* __restrict__ AU,
    unsigned int* __restrict__ bar, float omA)
{
    const int wg  = blockIdx.x;
    const int tid = threadIdx.x;
    __shared__ float sh[5440];
    __shared__ float part[32];
    __shared__ float rnsh[TB];

    const int bm = wg >> 3;
    const int i0 = (wg & 7) << 6;
    const int b  = bm >> 1, m = bm & 1;
    unsigned int ep = 0;

    // zero own slab
    {
        float4* M4 = (float4*)(Mm + ((size_t)bm * H_ + i0) * H_);
        for (int v = tid; v < (64 * H_) / 4; v += 512)
            M4[v] = make_float4(0.f, 0.f, 0.f, 0.f);
    }

    for (int blk = 0; blk <= NBLK; ++blk) {
        // ================= Phase C for blk-1 ================================
        if (blk > 0) {
            const int ct0 = (blk - 1) * TB;
            const int cTb = (LM1 - ct0 < TB) ? (LM1 - ct0) : TB;
            __syncthreads();
            if (tid < TB) rnsh[tid] = (tid < cTb) ? rn[(size_t)bm * LM1 + ct0 + tid] : 0.f;
            for (int v = tid; v < TB * 64; v += 512) {
                const int t = v >> 6, i2 = v & 63;
                sh[t * 68 + i2] = (t < cTb) ? AU[((size_t)bm * TB + t) * H_ + i0 + i2] : 0.f;
            }
            __syncthreads();
            const int j  = tid & 63;
            const int ig = tid >> 6;
            for (int jch = 0; jch < 8; ++jch) {
                const int j0 = jch << 6;
                for (int v = tid; v < TB * 64; v += 512) {
                    const int t = v >> 6, jj = v & 63;
                    sh[2720 + t * 68 + jj] = (t < cTb)
                        ? K[((size_t)(b * LM1 + ct0 + t)) * D_ + m * H_ + j0 + jj] * rnsh[t]
                        : 0.f;
                }
                __syncthreads();
                float acc[8];
#pragma unroll
                for (int q = 0; q < 8; ++q) acc[q] = 0.f;
                for (int t = 0; t < TB; ++t) {
                    const float kv = sh[2720 + t * 68 + j];
#pragma unroll
                    for (int q = 0; q < 8; ++q)
                        acc[q] = fmaf(sh[t * 68 + ig + (q << 3)], kv, acc[q]);
                }
#pragma unroll
                for (int q = 0; q < 8; ++q) {
                    float* p = Mm + ((size_t)bm * H_ + i0 + ig + (q << 3)) * H_ + j0 + j;
                    *p += acc[q];
                }
                __syncthreads();
            }
        }

        if (blk < NBLK) {
            const int t0 = blk * TB;
            const int Tb = (LM1 - t0 < TB) ? (LM1 - t0) : TB;

            // ================= Phase A ======================================
            {
                __syncthreads();
                if (tid < TB) rnsh[tid] = (tid < Tb) ? rn[(size_t)bm * LM1 + t0 + tid] : 0.f;
                __syncthreads();
                const int i  = tid & 63;
                const int tg = tid >> 6;
                float acc[5];
#pragma unroll
                for (int q = 0; q < 5; ++q) acc[q] = 0.f;
                for (int jch = 0; jch < 32; ++jch) {
                    const int j0 = jch << 4;
                    for (int v = tid; v < 1024; v += 512) {
                        const int i2 = v >> 4, jc = v & 15;
                        sh[i2 * 17 + jc] = Mm[((size_t)bm * H_ + i0 + i2) * H_ + j0 + jc];
                    }
                    for (int v = tid; v < TB * 16; v += 512) {
                        const int t2 = v >> 4, jc = v & 15;
                        sh[1088 + jc * 44 + t2] = (t2 < Tb)
                            ? K[((size_t)(b * LM1 + t0 + t2)) * D_ + m * H_ + j0 + jc] * rnsh[t2]
                            : 0.f;
                    }
                    __syncthreads();
#pragma unroll
                    for (int jc = 0; jc < 16; ++jc) {
                        const float mv = sh[i * 17 + jc];
#pragma unroll
                        for (int q = 0; q < 5; ++q)
                            acc[q] = fmaf(mv, sh[1088 + jc * 44 + tg + (q << 3)], acc[q]);
                    }
                    __syncthreads();
                }
#pragma unroll
                for (int q = 0; q < 5; ++q) {
                    const int t = tg + (q << 3);
                    if (t < Tb)
                        Vext[((size_t)bm * TB + t) * H_ + i0 + i] = acc[q];
                }
            }
            gbar(bar, ep);   // Vext ready

            // ================= Phase B ======================================
            if (wg < B_) {
                const int bq = wg;
                const int wid = tid >> 6, lane = tid & 63;
                {
                    const float4* g0 = (const float4*)(G + ((size_t)(bq*2+0) * NBLK + blk) * (TB*TB));
                    const float4* g1 = (const float4*)(G + ((size_t)(bq*2+1) * NBLK + blk) * (TB*TB));
                    if (tid < 400) {
                        ((float4*)sh)[tid]       = g0[tid];
                        ((float4*)sh)[400 + tid] = g1[tid];
                    }
                }
                float p00=0.f,p01=0.f,p02=0.f,p03=0.f,p04=0.f,p05=0.f,p06=0.f,p07=0.f;
                float p08=0.f,p09=0.f,p10=0.f,p11=0.f,p12=0.f,p13=0.f,p14=0.f,p15=0.f;
                float p16=0.f,p17=0.f,p18=0.f,p19=0.f,p20=0.f,p21=0.f,p22=0.f,p23=0.f;
                float p24=0.f,p25=0.f,p26=0.f,p27=0.f,p28=0.f,p29=0.f,p30=0.f,p31=0.f;
                float p32=0.f,p33=0.f,p34=0.f,p35=0.f,p36=0.f,p37=0.f,p38=0.f,p39=0.f;
                float q00=0.f,q01=0.f,q02=0.f,q03=0.f,q04=0.f,q05=0.f,q06=0.f,q07=0.f;
                float q08=0.f,q09=0.f,q10=0.f,q11=0.f,q12=0.f,q13=0.f,q14=0.f,q15=0.f;
                float q16=0.f,q17=0.f,q18=0.f,q19=0.f,q20=0.f,q21=0.f,q22=0.f,q23=0.f;
                float q24=0.f,q25=0.f,q26=0.f,q27=0.f,q28=0.f,q29=0.f,q30=0.f,q31=0.f;
                float q32=0.f,q33=0.f,q34=0.f,q35=0.f,q36=0.f,q37=0.f,q38=0.f,q39=0.f;
                __syncthreads();

                const float* Kb0 = K + ((size_t)(bq * LM1 + t0)) * D_ + tid;
                const float* Kb1 = Kb0 + H_;
                const float* Vb0 = Vext + ((size_t)(bq*2+0) * TB) * H_ + tid;
                const float* Vb1 = Vext + ((size_t)(bq*2+1) * TB) * H_ + tid;
                float* AU0 = AU + ((size_t)(bq*2+0) * TB) * H_ + tid;
                float* AU1 = AU + ((size_t)(bq*2+1) * TB) * H_ + tid;
                const float* qs = nk2 + (size_t)(bq*2+0) * LM1 + t0;
                const float* qe = nk2 + (size_t)(bq*2+1) * LM1 + t0;

                float kc0 = Kb0[0], kc1 = Kb1[0], vc0 = Vb0[0], vc1 = Vb1[0];
                float ncs = qs[0],  nce = qe[0];

                for (int t = 0; t < Tb; ++t) {
                    const float u0 = kc0 - vc0 - p00;
                    const float u1 = kc1 - vc1 - q00;
                    float kn0=0.f, kn1=0.f, vn0=0.f, vn1=0.f, nns=0.f, nne=0.f;
                    if (t + 1 < Tb) {
                        kn0 = Kb0[(size_t)(t+1) * D_]; kn1 = Kb1[(size_t)(t+1) * D_];
                        vn0 = Vb0[(t+1) * H_];         vn1 = Vb1[(t+1) * H_];
                        nns = qs[t+1];                 nne = qe[t+1];
                    }
                    float s0 = u0 * u0, s1 = u1 * u1;
#pragma unroll
                    for (int o = 32; o; o >>= 1) { s0 += __shfl_xor(s0, o); s1 += __shfl_xor(s1, o); }
                    float* pp = &part[(t & 1) << 4];
                    if (lane == 0) { pp[wid] = s0; pp[wid + 8] = s1; }
                    asm volatile("s_waitcnt lgkmcnt(0)" ::: "memory");
                    __builtin_amdgcn_s_barrier();
                    __builtin_amdgcn_sched_barrier(0);
                    float Ns = 0.f, Ne = 0.f;
#pragma unroll
                    for (int i = 0; i < 8; ++i) { Ns += pp[i]; Ne += pp[i + 8]; }
                    const bool fire = (Ns >= 0.49f * ncs) || (Ne >= 0.49f * nce);
                    const float w = (float)(t0 + t + 1) * (1.0f / (float)L_);
                    const float vv0 = fire ? omA * u0 : 0.f;
                    const float vv1 = fire ? omA * w * u1 : 0.f;
                    AU0[(size_t)t * H_] = vv0;
                    AU1[(size_t)t * H_] = vv1;

                    const float4* Gr0 = (const float4*)(sh + t * TB);
                    const float4* Gr1 = (const float4*)(sh + 1600 + t * TB);
                    float4 g;
                    g = Gr0[0];
                    p00 = fmaf(g.y, vv0, p01); p01 = fmaf(g.z, vv0, p02); p02 = fmaf(g.w, vv0, p03);
                    g = Gr0[1]; CH4(g, vv0, p03,p04,p05,p06,p07)
                    g = Gr0[2]; CH4(g, vv0, p07,p08,p09,p10,p11)
                    g = Gr0[3]; CH4(g, vv0, p11,p12,p13,p14,p15)
                    g = Gr0[4]; CH4(g, vv0, p15,p16,p17,p18,p19)
                    g = Gr0[5]; CH4(g, vv0, p19,p20,p21,p22,p23)
                    g = Gr0[6]; CH4(g, vv0, p23,p24,p25,p26,p27)
                    g = Gr0[7]; CH4(g, vv0, p27,p28,p29,p30,p31)
                    g = Gr0[8]; CH4(g, vv0, p31,p32,p33,p34,p35)
                    g = Gr0[9]; CH4(g, vv0, p35,p36,p37,p38,p39)
                    p39 = 0.f;
                    g = Gr1[0];
                    q00 = fmaf(g.y, vv1, q01); q01 = fmaf(g.z, vv1, q02); q02 = fmaf(g.w, vv1, q03);
                    g = Gr1[1]; CH4(g, vv1, q03,q04,q05,q06,q07)
                    g = Gr1[2]; CH4(g, vv1, q07,q08,q09,q10,q11)
                    g = Gr1[3]; CH4(g, vv1, q11,q12,q13,q14,q15)
                    g = Gr1[4]; CH4(g, vv1, q15,q16,q17,q18,q19)
                    g = Gr1[5]; CH4(g, vv1, q19,q20,q21,q22,q23)
                    g = Gr1[6]; CH4(g, vv1, q23,q24,q25,q26,q27)
                    g = Gr1[7]; CH4(g, vv1, q27,q28,q29,q30,q31)
                    g = Gr1[8]; CH4(g, vv1, q31,q32,q33,q34,q35)
                    g = Gr1[9]; CH4(g, vv1, q35,q36,q37,q38,q39)
                    q39 = 0.f;

                    kc0 = kn0; kc1 = kn1; vc0 = vn0; vc1 = vn1; ncs = nns; nce = nne;
                }
            }
            gbar(bar, ep);   // AU ready
        }
    }
}

// ---------------------------------------------------------------------------
// query path.  grid B_, block 1024
// ---------------------------------------------------------------------------
__global__ void __launch_bounds__(1024) k_q(
    const float* __restrict__ x, const float* __restrict__ Wsem,
    const float* __restrict__ Wepi, const float* __restrict__ nw,
    const float* __restrict__ nb, float* __restrict__ qn, float* __restrict__ gnull)
{
    const int b = blockIdx.x, tid = threadIdx.x;
    __shared__ float qsh[D_];
    __shared__ float red[16];
    qsh[tid] = x[((size_t)b * L_ + (L_ - 1)) * D_ + tid];
    __syncthreads();
    const float* wrow = (tid < H_) ? (Wsem + (size_t)tid * D_)
                                   : (Wepi + (size_t)(tid - H_) * D_);
    float s = 0.f;
    for (int d = 0; d < D_; d += 4) {
        const float4 w4 = *(const float4*)(wrow + d);
        s += qsh[d]*w4.x + qsh[d+1]*w4.y + qsh[d+2]*w4.z + qsh[d+3]*w4.w;
    }
    float sq = s * s;
#pragma unroll
    for (int o = 32; o; o >>= 1) sq += __shfl_xor(sq, o);
    const int wid = tid >> 6, lane = tid & 63;
    if (lane == 0) red[wid] = sq;
    __syncthreads();
    float n2s = 0.f, n2e = 0.f;
#pragma unroll
    for (int i = 0; i < 8; ++i) { n2s += red[i]; n2e += red[i + 8]; }
    const float rns = 1.f / fmaxf(sqrtf(n2s), 1e-12f);
    const float rne = 1.f / fmaxf(sqrtf(n2e), 1e-12f);
    qn[(size_t)b * D_ + tid] = s * ((tid < H_) ? rns : rne);
    if (wid == 0) {
        float g = 0.f;
        for (int d = lane * 4; d < D_; d += 256) {
            const float4 w4 = *(const float4*)(nw + d);
            g += qsh[d]*w4.x + qsh[d+1]*w4.y + qsh[d+2]*w4.z + qsh[d+3]*w4.w;
        }
#pragma unroll
        for (int o = 32; o; o >>= 1) g += __shfl_xor(g, o);
        if (lane == 0) gnull[b] = 1.f / (1.f + expf(-(g + nb[0])));
    }
}

// ---------------------------------------------------------------------------
__global__ void k_rmv(const float* __restrict__ M, const float* __restrict__ qn,
                      const float* __restrict__ gnull, float* __restrict__ rg)
{
    const int b = blockIdx.x;
    const int n = blockIdx.y * 4 + (threadIdx.x >> 6);
    const int lane = threadIdx.x & 63;
    const int m = n >> 9, i = n & 511;
    const float* Mr = M + ((size_t)(b*2+m) * H_ + i) * H_;
    const float* qv = qn + (size_t)b * D_ + m * H_;
    float s = 0.f;
#pragma unroll
    for (int it = 0; it < 2; ++it) {
        const int j = lane * 4 + it * 256;
        const float4 m4 = *(const float4*)(Mr + j);
        const float4 q4 = *(const float4*)(qv + j);
        s += m4.x*q4.x + m4.y*q4.y + m4.z*q4.z + m4.w*q4.w;
    }
#pragma unroll
    for (int o = 32; o; o >>= 1) s += __shfl_xor(s, o);
    if (lane == 0) rg[(size_t)b * D_ + n] = gnull[b] * s;
}

// ---------------------------------------------------------------------------
__global__ void k_out(const float* __restrict__ rg, const float* __restrict__ outw,
                      const float* __restrict__ outb, float* __restrict__ out)
{
    const int b = blockIdx.x;
    const int o = blockIdx.y * 4 + (threadIdx.x >> 6);
    const int lane = threadIdx.x & 63;
    const float* wr = outw + (size_t)o * D_;
    const float* rv = rg + (size_t)b * D_;
    float s = 0.f;
#pragma unroll
    for (int it = 0; it < 4; ++it) {
        const int j = lane * 4 + it * 256;
        const float4 w4 = *(const float4*)(wr + j);
        const float4 r4 = *(const float4*)(rv + j);
        s += w4.x*r4.x + w4.y*r4.y + w4.z*r4.z + w4.w*r4.w;
    }
#pragma unroll
    for (int o2 = 32; o2; o2 >>= 1) s += __shfl_xor(s, o2);
    if (lane == 0) out[(size_t)b * D_ + o] = s + outb[o];
}

// ---------------------------------------------------------------------------
extern "C" void kernel_launch(void* const* d_in, const int* in_sizes, int n_in,
                              void* d_out, int out_size, void* d_ws, size_t ws_size,
                              hipStream_t stream)
{
    (void)in_sizes; (void)n_in; (void)out_size;
    const float* x     = (const float*)d_in[0];
    const float* Wsem  = (const float*)d_in[1];
    const float* Wepi  = (const float*)d_in[2];
    const float* nullw = (const float*)d_in[3];
    const float* nullb = (const float*)d_in[4];
    const float* outw  = (const float*)d_in[5];
    const float* outb  = (const float*)d_in[6];
    float* out = (float*)d_out;

    float* ws = (float*)d_ws;
    size_t off = 0;
    float* K     = ws + off; off += (size_t)B_ * LM1 * D_;
    float* nk2   = ws + off; off += (size_t)B_ * 2 * LM1;
    float* rn    = ws + off; off += (size_t)B_ * 2 * LM1;
    float* Mm    = ws + off; off += (size_t)B_ * 2 * H_ * H_;
    float* Vext  = ws + off; off += (size_t)B_ * 2 * TB * H_;
    float* G     = ws + off; off += (size_t)B_ * 2 * NBLK * TB * TB;
    float* AU    = ws + off; off += (size_t)B_ * 2 * TB * H_;
    float* qn    = ws + off; off += (size_t)B_ * D_;
    float* gnull = ws + off; off += (size_t)B_;
    float* rg    = ws + off; off += (size_t)B_ * D_;
    float* barf  = ws + off; off += 64;           // grid-barrier counter (isolated line)
    if (ws_size < off * sizeof(float)) return;
    unsigned int* bar = (unsigned int*)barf;

    float omA = (float)(1.0 - pow(0.95, 96.0 / 2048.0));

    hipMemsetAsync(barf, 0, 64 * sizeof(float), stream);   // epoch counter = 0

    k_proj <<<dim3(512, 16), 256, 0, stream>>>(x, Wsem, Wepi, K);
    k_norms<<<dim3(B_ * LM1), 256, 0, stream>>>(K, nk2, rn);
    k_gram <<<dim3(NBLK, B_ * 2), 256, 0, stream>>>(K, rn, G);

    {
        void* args[] = { (void*)&K, (void*)&rn, (void*)&nk2, (void*)&G,
                         (void*)&Mm, (void*)&Vext, (void*)&AU, (void*)&bar, (void*)&omA };
        hipLaunchCooperativeKernel((void*)k_scan, dim3(NWG), dim3(512), args, 0, stream);
    }

    k_q  <<<dim3(B_), 1024, 0, stream>>>(x, Wsem, Wepi, nullw, nullb, qn, gnull);
    k_rmv<<<dim3(16, 256), 256, 0, stream>>>(Mm, qn, gnull, rg);
    k_out<<<dim3(16, 256), 256, 0, stream>>>(rg, outw, outb, out);
}

// Round 10
// 9863.089 us; speedup vs baseline: 22.0189x; 1.0547x over previous
//
#include <hip/hip_runtime.h>
#include <math.h>

#define B_    16
#define L_    2048
#define LM1   2047
#define D_    1024
#define H_    512
#define TB    40
#define NBLK  52    // 52*40 = 2080 >= 2047
#define NWG   256

// dynamic LDS layout (floats): M slab 32768 | scratch 5440 | part 32 | rnsh 40
#define SH_FLOATS (32768 + 5440 + 32 + 40)
#define SH_BYTES  (SH_FLOATS * 4)

// ---------------------------------------------------------------------------
// coherent (coherence-point) access helpers: no cache-invalidate side effects.
// ---------------------------------------------------------------------------
__device__ __forceinline__ float cload(const float* p)
{
    float v;
    asm volatile("global_load_dword %0, %1, off sc0 sc1\n\ts_waitcnt vmcnt(0)"
                 : "=v"(v) : "v"(p) : "memory");
    return v;
}
__device__ __forceinline__ void cload2(const float* p0, const float* p1,
                                       float& a, float& b)
{
    asm volatile("global_load_dword %0, %2, off sc0 sc1\n\t"
                 "global_load_dword %1, %3, off sc0 sc1\n\t"
                 "s_waitcnt vmcnt(0)"
                 : "=&v"(a), "=&v"(b) : "v"(p0), "v"(p1) : "memory");
}
__device__ __forceinline__ void cstore(float* p, float v)
{
    asm volatile("global_store_dword %0, %1, off sc0 sc1" :: "v"(p), "v"(v) : "memory");
}
__device__ __forceinline__ unsigned int bar_poll(const unsigned int* p)
{
    unsigned int v;
    asm volatile("global_load_dword %0, %1, off sc0 sc1\n\ts_waitcnt vmcnt(0)"
                 : "=v"(v) : "v"(p) : "memory");
    return v;
}

// grid barrier: round-9 proven protocol; release(wb) only, NO acquire-inv
// (cross-WG data travels via sc0sc1 write-through + sc0sc1 loads, so L2 of
// read-only K/G/nk2 stays warm across the whole scan).
__device__ __forceinline__ void gbar(unsigned int* bar, unsigned int& ep)
{
    __syncthreads();
    if (threadIdx.x == 0) {
        __builtin_amdgcn_fence(__ATOMIC_RELEASE, "agent");
        ep += NWG;
        __hip_atomic_fetch_add(bar, 1u, __ATOMIC_RELAXED, __HIP_MEMORY_SCOPE_AGENT);
        while (bar_poll(bar) < ep)
            __builtin_amdgcn_s_sleep(16);
    }
    __syncthreads();
}

// ---------------------------------------------------------------------------
// K[r][n] = sum_d x[b*L+t][d] * Wcat[n][d]   grid (512,16), block 256
// ---------------------------------------------------------------------------
__global__ void k_proj(const float* __restrict__ x, const float* __restrict__ Wsem,
                       const float* __restrict__ Wepi, float* __restrict__ K)
{
    __shared__ float As[16][68];
    __shared__ float Bs[16][68];
    const int tid = threadIdx.x;
    const int tx = tid & 15, ty = tid >> 4;
    const int r0 = blockIdx.x * 64;
    const int n0 = blockIdx.y * 64;
    const int lr  = tid >> 2;
    const int lk4 = (tid & 3) << 2;
    const int rowg = r0 + lr;
    const bool rok = rowg < B_ * LM1;
    const int rowc = rok ? rowg : 0;
    const int bb = rowc / LM1;
    const int tt = rowc - bb * LM1;
    const float* xrow = x + ((size_t)bb * L_ + tt) * D_;
    const int nW = n0 + lr;
    const float* wrow = (nW < H_) ? (Wsem + (size_t)nW * D_)
                                  : (Wepi + (size_t)(nW - H_) * D_);
    float acc[4][4];
#pragma unroll
    for (int i = 0; i < 4; ++i)
#pragma unroll
        for (int j = 0; j < 4; ++j) acc[i][j] = 0.f;

    for (int kk = 0; kk < D_; kk += 16) {
        const float4 av = rok ? *(const float4*)(xrow + kk + lk4) : make_float4(0.f,0.f,0.f,0.f);
        const float4 bv = *(const float4*)(wrow + kk + lk4);
        As[lk4+0][lr] = av.x; As[lk4+1][lr] = av.y; As[lk4+2][lr] = av.z; As[lk4+3][lr] = av.w;
        Bs[lk4+0][lr] = bv.x; Bs[lk4+1][lr] = bv.y; Bs[lk4+2][lr] = bv.z; Bs[lk4+3][lr] = bv.w;
        __syncthreads();
#pragma unroll
        for (int k = 0; k < 16; ++k) {
            const float4 a4 = *(const float4*)&As[k][ty << 2];
            const float4 b4 = *(const float4*)&Bs[k][tx << 2];
            const float aa[4] = {a4.x, a4.y, a4.z, a4.w};
            const float bbv[4] = {b4.x, b4.y, b4.z, b4.w};
#pragma unroll
            for (int i = 0; i < 4; ++i)
#pragma unroll
                for (int j = 0; j < 4; ++j)
                    acc[i][j] = fmaf(aa[i], bbv[j], acc[i][j]);
        }
        __syncthreads();
    }
#pragma unroll
    for (int i = 0; i < 4; ++i) {
        const int r = r0 + (ty << 2) + i;
        if (r < B_ * LM1)
            *(float4*)(K + (size_t)r * D_ + n0 + (tx << 2)) =
                make_float4(acc[i][0], acc[i][1], acc[i][2], acc[i][3]);
    }
}

// ---------------------------------------------------------------------------
// norms.  grid B_*LM1, block 256
// ---------------------------------------------------------------------------
__global__ void k_norms(const float* __restrict__ K, float* __restrict__ nk2,
                        float* __restrict__ rn)
{
    const int r = blockIdx.x;
    const int tid = threadIdx.x;
    const float4 v = *(const float4*)(K + (size_t)r * D_ + (tid << 2));
    float s = v.x*v.x + v.y*v.y + v.z*v.z + v.w*v.w;
#pragma unroll
    for (int o = 32; o; o >>= 1) s += __shfl_xor(s, o);
    __shared__ float part[4];
    const int wid = tid >> 6, lane = tid & 63;
    if (lane == 0) part[wid] = s;
    __syncthreads();
    if (tid == 0) {
        const int b = r / LM1, t = r - b * LM1;
        const float s0 = part[0] + part[1];
        const float s1 = part[2] + part[3];
        nk2[(size_t)(b*2+0)*LM1 + t] = s0;
        nk2[(size_t)(b*2+1)*LM1 + t] = s1;
        rn [(size_t)(b*2+0)*LM1 + t] = 1.f / fmaxf(sqrtf(s0), 1e-12f);
        rn [(size_t)(b*2+1)*LM1 + t] = 1.f / fmaxf(sqrtf(s1), 1e-12f);
    }
}

// ---------------------------------------------------------------------------
// Gram, shifted layout: G[bm][blk][t*TB+d] = kn_t . kn_{t+d}, 0 if OOB.
// grid (NBLK, 32), block 256.
// ---------------------------------------------------------------------------
__global__ void k_gram(const float* __restrict__ K, const float* __restrict__ rn,
                       float* __restrict__ G)
{
    __shared__ float rows[TB * 129];
    const int blk = blockIdx.x, bm = blockIdx.y;
    const int b = bm >> 1, m = bm & 1;
    const int t0 = blk * TB;
    const int Tb = (LM1 - t0 < TB) ? (LM1 - t0) : TB;
    const int tid = threadIdx.x;

    float acc[7];
#pragma unroll
    for (int e = 0; e < 7; ++e) acc[e] = 0.f;

    for (int c0 = 0; c0 < H_; c0 += 128) {
        for (int v = tid; v < TB * 128; v += 256) {
            const int t = v >> 7, c = v & 127;
            float val = 0.f;
            if (t < Tb)
                val = K[((size_t)(b * LM1 + t0 + t)) * D_ + m * H_ + c0 + c]
                    * rn[(size_t)bm * LM1 + t0 + t];
            rows[t * 129 + c] = val;
        }
        __syncthreads();
        for (int e = 0; e < 7; ++e) {
            const int idx = e * 256 + tid;
            if (idx < TB * TB) {
                const int t = idx / TB, d = idx - t * TB;
                if (t + d < Tb) {
                    const float* ra = rows + t * 129;
                    const float* rb = rows + (t + d) * 129;
                    float s = acc[e];
                    for (int c = 0; c < 128; ++c) s = fmaf(ra[c], rb[c], s);
                    acc[e] = s;
                }
            }
        }
        __syncthreads();
    }
    float* Gout = G + ((size_t)bm * NBLK + blk) * (TB * TB);
    for (int e = 0; e < 7; ++e) {
        const int idx = e * 256 + tid;
        if (idx < TB * TB) {
            const int t = idx / TB, d = idx - t * TB;
            Gout[idx] = (t + d < Tb) ? acc[e] : 0.f;
        }
    }
}

// pending-shift chunk
#define CH4(g,vvx,pA,pB,pC,pD,pE) \
    pA = fmaf(g.x, vvx, pB); pB = fmaf(g.y, vvx, pC); \
    pC = fmaf(g.z, vvx, pD); pD = fmaf(g.w, vvx, pE);

// ---------------------------------------------------------------------------
// Fused scan with M PERMANENTLY IN LDS (128 KB slab per WG, XOR-swizzled).
// Storage map: logical (i,j) -> Mlds[i*512 + (((j>>2) ^ (i&7))<<2) + (j&3)]
// -> A's b128 reads of (i, c4-block) are conflict-free; C's scalar RMW 2-way.
// ---------------------------------------------------------------------------
__global__ void __launch_bounds__(512, 2) k_scan(
    const float* __restrict__ K, const float* __restrict__ rn,
    const float* __restrict__ nk2, const float* __restrict__ G,
    float* __restrict__ Mm, float* __restrict__ Vext, float* __restrict__ AU,
    unsigned int* __restrict__ bar, float omA)
{
    extern __shared__ __align__(16) float dyn[];
    float* Mlds = dyn;                   // 32768
    float* sh   = dyn + 32768;           // 5440 scratch
    float* part = dyn + 32768 + 5440;    // 32
    float* rnsh = dyn + 32768 + 5472;    // 40

    const int wg  = blockIdx.x;
    const int tid = threadIdx.x;
    const int bm = wg >> 3;
    const int i0 = (wg & 7) << 6;
    const int b  = bm >> 1, m = bm & 1;
    unsigned int ep = 0;

    // zero LDS-resident M slab
    for (int v = tid; v < 32768; v += 512) Mlds[v] = 0.f;

    for (int blk = 0; blk <= NBLK; ++blk) {
        // ================= Phase C for blk-1: Mlds += AU^T (rn o K) =========
        if (blk > 0) {
            const int ct0 = (blk - 1) * TB;
            const int cTb = (LM1 - ct0 < TB) ? (LM1 - ct0) : TB;
            __syncthreads();
            if (tid < TB) rnsh[tid] = (tid < cTb) ? rn[(size_t)bm * LM1 + ct0 + tid] : 0.f;
            for (int v = tid; v < TB * 64; v += 512) {
                const int t = v >> 6, i2 = v & 63;
                sh[t * 68 + i2] = (t < cTb)
                    ? cload(&AU[((size_t)bm * TB + t) * H_ + i0 + i2]) : 0.f;
            }
            __syncthreads();
            const int j  = tid & 63;
            const int ig = tid >> 6;
            for (int jch = 0; jch < 8; ++jch) {
                const int j0 = jch << 6;
                for (int v = tid; v < TB * 64; v += 512) {
                    const int t = v >> 6, jj = v & 63;
                    sh[2720 + t * 68 + jj] = (t < cTb)
                        ? K[((size_t)(b * LM1 + ct0 + t)) * D_ + m * H_ + j0 + jj] * rnsh[t]
                        : 0.f;
                }
                __syncthreads();
                float acc2[8];
#pragma unroll
                for (int q = 0; q < 8; ++q) acc2[q] = 0.f;
                for (int t = 0; t < TB; ++t) {
                    const float kv = sh[2720 + t * 68 + j];
#pragma unroll
                    for (int q = 0; q < 8; ++q)
                        acc2[q] = fmaf(sh[t * 68 + ig + (q << 3)], kv, acc2[q]);
                }
#pragma unroll
                for (int q = 0; q < 8; ++q) {
                    const int r  = ig + (q << 3);
                    const int jg = j0 + j;
                    Mlds[(r << 9) + ((((jg >> 2) ^ (r & 7)) << 2)) + (jg & 3)] += acc2[q];
                }
                __syncthreads();
            }
        }

        if (blk < NBLK) {
            const int t0 = blk * TB;
            const int Tb = (LM1 - t0 < TB) ? (LM1 - t0) : TB;

            // ================= Phase A: Vext = rn o (K_blk @ Mlds^T) ========
            {
                __syncthreads();
                if (tid < TB) rnsh[tid] = (tid < Tb) ? rn[(size_t)bm * LM1 + t0 + tid] : 0.f;
                __syncthreads();
                const int i  = tid & 63;
                const int tg = tid >> 6;
                const int sw = i & 7;
                const float4* M4 = (const float4*)Mlds;
                float acc[5];
#pragma unroll
                for (int q = 0; q < 5; ++q) acc[q] = 0.f;
                for (int jch = 0; jch < 32; ++jch) {
                    const int j0 = jch << 4;
                    for (int v = tid; v < TB * 16; v += 512) {
                        const int t2 = v >> 4, jc = v & 15;
                        sh[v] = (t2 < Tb)
                            ? K[((size_t)(b * LM1 + t0 + t2)) * D_ + m * H_ + j0 + jc] * rnsh[t2]
                            : 0.f;
                    }
                    __syncthreads();
                    const float4* Ks4 = (const float4*)sh;   // [t*4 + jc4]
#pragma unroll
                    for (int jc4 = 0; jc4 < 4; ++jc4) {
                        const float4 m4 = M4[(i << 7) + (((jch << 2) + jc4) ^ sw)];
#pragma unroll
                        for (int q = 0; q < 5; ++q) {
                            const float4 k4 = Ks4[((tg + (q << 3)) << 2) + jc4];
                            acc[q] = fmaf(m4.x, k4.x, fmaf(m4.y, k4.y,
                                     fmaf(m4.z, k4.z, fmaf(m4.w, k4.w, acc[q]))));
                        }
                    }
                    __syncthreads();
                }
#pragma unroll
                for (int q = 0; q < 5; ++q) {
                    const int t = tg + (q << 3);
                    if (t < Tb)
                        cstore(&Vext[((size_t)bm * TB + t) * H_ + i0 + i], acc[q]);
                }
            }
            gbar(bar, ep);   // Vext ready (sc write-through + drained at sync)

            // ================= Phase B (WGs 0..15): sequential scan ==========
            if (wg < B_) {
                const int bq = wg;
                const int wid = tid >> 6, lane = tid & 63;
                {
                    const float4* g0 = (const float4*)(G + ((size_t)(bq*2+0) * NBLK + blk) * (TB*TB));
                    const float4* g1 = (const float4*)(G + ((size_t)(bq*2+1) * NBLK + blk) * (TB*TB));
                    if (tid < 400) {
                        ((float4*)sh)[tid]       = g0[tid];
                        ((float4*)sh)[400 + tid] = g1[tid];
                    }
                }
                float p00=0.f,p01=0.f,p02=0.f,p03=0.f,p04=0.f,p05=0.f,p06=0.f,p07=0.f;
                float p08=0.f,p09=0.f,p10=0.f,p11=0.f,p12=0.f,p13=0.f,p14=0.f,p15=0.f;
                float p16=0.f,p17=0.f,p18=0.f,p19=0.f,p20=0.f,p21=0.f,p22=0.f,p23=0.f;
                float p24=0.f,p25=0.f,p26=0.f,p27=0.f,p28=0.f,p29=0.f,p30=0.f,p31=0.f;
                float p32=0.f,p33=0.f,p34=0.f,p35=0.f,p36=0.f,p37=0.f,p38=0.f,p39=0.f;
                float q00=0.f,q01=0.f,q02=0.f,q03=0.f,q04=0.f,q05=0.f,q06=0.f,q07=0.f;
                float q08=0.f,q09=0.f,q10=0.f,q11=0.f,q12=0.f,q13=0.f,q14=0.f,q15=0.f;
                float q16=0.f,q17=0.f,q18=0.f,q19=0.f,q20=0.f,q21=0.f,q22=0.f,q23=0.f;
                float q24=0.f,q25=0.f,q26=0.f,q27=0.f,q28=0.f,q29=0.f,q30=0.f,q31=0.f;
                float q32=0.f,q33=0.f,q34=0.f,q35=0.f,q36=0.f,q37=0.f,q38=0.f,q39=0.f;
                __syncthreads();

                const float* Kb0 = K + ((size_t)(bq * LM1 + t0)) * D_ + tid;
                const float* Kb1 = Kb0 + H_;
                const float* Vb0 = Vext + ((size_t)(bq*2+0) * TB) * H_ + tid;
                const float* Vb1 = Vext + ((size_t)(bq*2+1) * TB) * H_ + tid;
                float* AU0 = AU + ((size_t)(bq*2+0) * TB) * H_ + tid;
                float* AU1 = AU + ((size_t)(bq*2+1) * TB) * H_ + tid;
                const float* qs = nk2 + (size_t)(bq*2+0) * LM1 + t0;
                const float* qe = nk2 + (size_t)(bq*2+1) * LM1 + t0;

                float kc0 = Kb0[0], kc1 = Kb1[0];
                float ncs = qs[0],  nce = qe[0];

                for (int t = 0; t < Tb; ++t) {
                    float vt0, vt1;
                    cload2(Vb0 + (size_t)t * H_, Vb1 + (size_t)t * H_, vt0, vt1);
                    const float u0 = kc0 - vt0 - p00;
                    const float u1 = kc1 - vt1 - q00;
                    float kn0=0.f, kn1=0.f, nns=0.f, nne=0.f;
                    if (t + 1 < Tb) {
                        kn0 = Kb0[(size_t)(t+1) * D_]; kn1 = Kb1[(size_t)(t+1) * D_];
                        nns = qs[t+1];                 nne = qe[t+1];
                    }
                    float s0 = u0 * u0, s1 = u1 * u1;
#pragma unroll
                    for (int o = 32; o; o >>= 1) { s0 += __shfl_xor(s0, o); s1 += __shfl_xor(s1, o); }
                    float* pp = &part[(t & 1) << 4];
                    if (lane == 0) { pp[wid] = s0; pp[wid + 8] = s1; }
                    asm volatile("s_waitcnt lgkmcnt(0)" ::: "memory");
                    __builtin_amdgcn_s_barrier();
                    __builtin_amdgcn_sched_barrier(0);
                    float Ns = 0.f, Ne = 0.f;
#pragma unroll
                    for (int i = 0; i < 8; ++i) { Ns += pp[i]; Ne += pp[i + 8]; }
                    const bool fire = (Ns >= 0.49f * ncs) || (Ne >= 0.49f * nce);
                    const float w = (float)(t0 + t + 1) * (1.0f / (float)L_);
                    const float vv0 = fire ? omA * u0 : 0.f;
                    const float vv1 = fire ? omA * w * u1 : 0.f;
                    cstore(AU0 + (size_t)t * H_, vv0);
                    cstore(AU1 + (size_t)t * H_, vv1);

                    const float4* Gr0 = (const float4*)(sh + t * TB);
                    const float4* Gr1 = (const float4*)(sh + 1600 + t * TB);
                    float4 g;
                    g = Gr0[0];
                    p00 = fmaf(g.y, vv0, p01); p01 = fmaf(g.z, vv0, p02); p02 = fmaf(g.w, vv0, p03);
                    g = Gr0[1]; CH4(g, vv0, p03,p04,p05,p06,p07)
                    g = Gr0[2]; CH4(g, vv0, p07,p08,p09,p10,p11)
                    g = Gr0[3]; CH4(g, vv0, p11,p12,p13,p14,p15)
                    g = Gr0[4]; CH4(g, vv0, p15,p16,p17,p18,p19)
                    g = Gr0[5]; CH4(g, vv0, p19,p20,p21,p22,p23)
                    g = Gr0[6]; CH4(g, vv0, p23,p24,p25,p26,p27)
                    g = Gr0[7]; CH4(g, vv0, p27,p28,p29,p30,p31)
                    g = Gr0[8]; CH4(g, vv0, p31,p32,p33,p34,p35)
                    g = Gr0[9]; CH4(g, vv0, p35,p36,p37,p38,p39)
                    p39 = 0.f;
                    g = Gr1[0];
                    q00 = fmaf(g.y, vv1, q01); q01 = fmaf(g.z, vv1, q02); q02 = fmaf(g.w, vv1, q03);
                    g = Gr1[1]; CH4(g, vv1, q03,q04,q05,q06,q07)
                    g = Gr1[2]; CH4(g, vv1, q07,q08,q09,q10,q11)
                    g = Gr1[3]; CH4(g, vv1, q11,q12,q13,q14,q15)
                    g = Gr1[4]; CH4(g, vv1, q15,q16,q17,q18,q19)
                    g = Gr1[5]; CH4(g, vv1, q19,q20,q21,q22,q23)
                    g = Gr1[6]; CH4(g, vv1, q23,q24,q25,q26,q27)
                    g = Gr1[7]; CH4(g, vv1, q27,q28,q29,q30,q31)
                    g = Gr1[8]; CH4(g, vv1, q31,q32,q33,q34,q35)
                    g = Gr1[9]; CH4(g, vv1, q35,q36,q37,q38,q39)
                    q39 = 0.f;

                    kc0 = kn0; kc1 = kn1; ncs = nns; nce = nne;
                }
            }
            gbar(bar, ep);   // AU ready
        }
    }

    // flush LDS-resident M to global for the query path
    __syncthreads();
    for (int v = tid; v < 64 * H_; v += 512) {
        const int il = v >> 9, jg = v & 511;
        Mm[((size_t)bm * H_ + i0 + il) * H_ + jg] =
            Mlds[(il << 9) + ((((jg >> 2) ^ (il & 7)) << 2)) + (jg & 3)];
    }
}

// ---------------------------------------------------------------------------
// query path.  grid B_, block 1024
// ---------------------------------------------------------------------------
__global__ void __launch_bounds__(1024) k_q(
    const float* __restrict__ x, const float* __restrict__ Wsem,
    const float* __restrict__ Wepi, const float* __restrict__ nw,
    const float* __restrict__ nb, float* __restrict__ qn, float* __restrict__ gnull)
{
    const int b = blockIdx.x, tid = threadIdx.x;
    __shared__ float qsh[D_];
    __shared__ float red[16];
    qsh[tid] = x[((size_t)b * L_ + (L_ - 1)) * D_ + tid];
    __syncthreads();
    const float* wrow = (tid < H_) ? (Wsem + (size_t)tid * D_)
                                   : (Wepi + (size_t)(tid - H_) * D_);
    float s = 0.f;
    for (int d = 0; d < D_; d += 4) {
        const float4 w4 = *(const float4*)(wrow + d);
        s += qsh[d]*w4.x + qsh[d+1]*w4.y + qsh[d+2]*w4.z + qsh[d+3]*w4.w;
    }
    float sq = s * s;
#pragma unroll
    for (int o = 32; o; o >>= 1) sq += __shfl_xor(sq, o);
    const int wid = tid >> 6, lane = tid & 63;
    if (lane == 0) red[wid] = sq;
    __syncthreads();
    float n2s = 0.f, n2e = 0.f;
#pragma unroll
    for (int i = 0; i < 8; ++i) { n2s += red[i]; n2e += red[i + 8]; }
    const float rns = 1.f / fmaxf(sqrtf(n2s), 1e-12f);
    const float rne = 1.f / fmaxf(sqrtf(n2e), 1e-12f);
    qn[(size_t)b * D_ + tid] = s * ((tid < H_) ? rns : rne);
    if (wid == 0) {
        float g = 0.f;
        for (int d = lane * 4; d < D_; d += 256) {
            const float4 w4 = *(const float4*)(nw + d);
            g += qsh[d]*w4.x + qsh[d+1]*w4.y + qsh[d+2]*w4.z + qsh[d+3]*w4.w;
        }
#pragma unroll
        for (int o = 32; o; o >>= 1) g += __shfl_xor(g, o);
        if (lane == 0) gnull[b] = 1.f / (1.f + expf(-(g + nb[0])));
    }
}

// ---------------------------------------------------------------------------
__global__ void k_rmv(const float* __restrict__ M, const float* __restrict__ qn,
                      const float* __restrict__ gnull, float* __restrict__ rg)
{
    const int b = blockIdx.x;
    const int n = blockIdx.y * 4 + (threadIdx.x >> 6);
    const int lane = threadIdx.x & 63;
    const int m = n >> 9, i = n & 511;
    const float* Mr = M + ((size_t)(b*2+m) * H_ + i) * H_;
    const float* qv = qn + (size_t)b * D_ + m * H_;
    float s = 0.f;
#pragma unroll
    for (int it = 0; it < 2; ++it) {
        const int j = lane * 4 + it * 256;
        const float4 m4 = *(const float4*)(Mr + j);
        const float4 q4 = *(const float4*)(qv + j);
        s += m4.x*q4.x + m4.y*q4.y + m4.z*q4.z + m4.w*q4.w;
    }
#pragma unroll
    for (int o = 32; o; o >>= 1) s += __shfl_xor(s, o);
    if (lane == 0) rg[(size_t)b * D_ + n] = gnull[b] * s;
}

// ---------------------------------------------------------------------------
__global__ void k_out(const float* __restrict__ rg, const float* __restrict__ outw,
                      const float* __restrict__ outb, float* __restrict__ out)
{
    const int b = blockIdx.x;
    const int o = blockIdx.y * 4 + (threadIdx.x >> 6);
    const int lane = threadIdx.x & 63;
    const float* wr = outw + (size_t)o * D_;
    const float* rv = rg + (size_t)b * D_;
    float s = 0.f;
#pragma unroll
    for (int it = 0; it < 4; ++it) {
        const int j = lane * 4 + it * 256;
        const float4 w4 = *(const float4*)(wr + j);
        const float4 r4 = *(const float4*)(rv + j);
        s += w4.x*r4.x + w4.y*r4.y + w4.z*r4.z + w4.w*r4.w;
    }
#pragma unroll
    for (int o2 = 32; o2; o2 >>= 1) s += __shfl_xor(s, o2);
    if (lane == 0) out[(size_t)b * D_ + o] = s + outb[o];
}

// ---------------------------------------------------------------------------
extern "C" void kernel_launch(void* const* d_in, const int* in_sizes, int n_in,
                              void* d_out, int out_size, void* d_ws, size_t ws_size,
                              hipStream_t stream)
{
    (void)in_sizes; (void)n_in; (void)out_size;
    const float* x     = (const float*)d_in[0];
    const float* Wsem  = (const float*)d_in[1];
    const float* Wepi  = (const float*)d_in[2];
    const float* nullw = (const float*)d_in[3];
    const float* nullb = (const float*)d_in[4];
    const float* outw  = (const float*)d_in[5];
    const float* outb  = (const float*)d_in[6];
    float* out = (float*)d_out;

    float* ws = (float*)d_ws;
    size_t off = 0;
    float* K     = ws + off; off += (size_t)B_ * LM1 * D_;
    float* nk2   = ws + off; off += (size_t)B_ * 2 * LM1;
    float* rn    = ws + off; off += (size_t)B_ * 2 * LM1;
    float* Mm    = ws + off; off += (size_t)B_ * 2 * H_ * H_;
    float* Vext  = ws + off; off += (size_t)B_ * 2 * TB * H_;
    float* G     = ws + off; off += (size_t)B_ * 2 * NBLK * TB * TB;
    float* AU    = ws + off; off += (size_t)B_ * 2 * TB * H_;
    float* qn    = ws + off; off += (size_t)B_ * D_;
    float* gnull = ws + off; off += (size_t)B_;
    float* rg    = ws + off; off += (size_t)B_ * D_;
    float* barf  = ws + off; off += 64;           // grid-barrier counter
    if (ws_size < off * sizeof(float)) return;
    unsigned int* bar = (unsigned int*)barf;

    float omA = (float)(1.0 - pow(0.95, 96.0 / 2048.0));

    hipMemsetAsync(barf, 0, 64 * sizeof(float), stream);   // epoch counter = 0

    k_proj <<<dim3(512, 16), 256, 0, stream>>>(x, Wsem, Wepi, K);
    k_norms<<<dim3(B_ * LM1), 256, 0, stream>>>(K, nk2, rn);
    k_gram <<<dim3(NBLK, B_ * 2), 256, 0, stream>>>(K, rn, G);

    {
        static int attr_set = 0;
        if (!attr_set) {
            hipFuncSetAttribute((const void*)k_scan,
                                hipFuncAttributeMaxDynamicSharedMemorySize, SH_BYTES);
            attr_set = 1;
        }
        void* args[] = { (void*)&K, (void*)&rn, (void*)&nk2, (void*)&G,
                         (void*)&Mm, (void*)&Vext, (void*)&AU, (void*)&bar, (void*)&omA };
        hipLaunchCooperativeKernel((void*)k_scan, dim3(NWG), dim3(512), args,
                                   SH_BYTES, stream);
    }

    k_q  <<<dim3(B_), 1024, 0, stream>>>(x, Wsem, Wepi, nullw, nullb, qn, gnull);
    k_rmv<<<dim3(16, 256), 256, 0, stream>>>(Mm, qn, gnull, rg);
    k_out<<<dim3(16, 256), 256, 0, stream>>>(rg, outw, outb, out);
}